// Round 3
// baseline (2075.703 us; speedup 1.0000x reference)
//
#include <hip/hip_runtime.h>

static constexpr int NN = 100000;    // nodes
static constexpr int EE = 1600000;   // edges (before self-loops)
static constexpr int BSZ = 64;       // nodes per bucket
static constexpr int NB = (NN + BSZ - 1) / BSZ;   // 1563 buckets
static constexpr int TILE = 4096;    // edges per k_bin block

// ---------------- degree histogram / dinv ----------------

__global__ __launch_bounds__(256) void k_count(const int* __restrict__ dst,
                                               int* __restrict__ cnt, int E) {
    int i = blockIdx.x * 256 + threadIdx.x;
    if (i < E) atomicAdd(&cnt[dst[i]], 1);
}

__global__ __launch_bounds__(256) void k_dinv(const int* __restrict__ cnt,
                                              float* __restrict__ dinv, int n) {
    int i = blockIdx.x * 256 + threadIdx.x;
    if (i < n) dinv[i] = rsqrtf((float)cnt[i] + 1.0f);  // +1 self-loop
}

// ---------------- bucket counts: bcnt[b] = sum cnt[b*64 .. b*64+63] --------

__global__ __launch_bounds__(256) void k_bsum(const int* __restrict__ cnt,
                                              int* __restrict__ bcnt, int n, int nb) {
    const int b = blockIdx.x * 4 + (threadIdx.x >> 6);
    const int lane = threadIdx.x & 63;
    if (b >= nb) return;
    const int node = b * BSZ + lane;
    int v = (node < n) ? cnt[node] : 0;
#pragma unroll
    for (int m = 32; m >= 1; m >>= 1) v += __shfl_xor(v, m, 64);
    if (lane == 0) bcnt[b] = v;
}

// ---------------- exclusive scan of bcnt -> bbase[NB+1], init bcur ---------

__global__ __launch_bounds__(256) void k_scanb(const int* __restrict__ bcnt,
                                               int* __restrict__ bbase,
                                               int* __restrict__ bcur, int nb) {
    constexpr int PT = 7;  // 256*7 = 1792 >= NB
    __shared__ int sd[256];
    const int t = threadIdx.x;
    int vals[PT];
    int s = 0;
#pragma unroll
    for (int k = 0; k < PT; ++k) {
        int idx = t * PT + k;
        vals[k] = (idx < nb) ? bcnt[idx] : 0;
        s += vals[k];
    }
    sd[t] = s;
    __syncthreads();
    for (int off = 1; off < 256; off <<= 1) {
        int v = (t >= off) ? sd[t - off] : 0;
        __syncthreads();
        sd[t] += v;
        __syncthreads();
    }
    int run = (t == 0) ? 0 : sd[t - 1];
#pragma unroll
    for (int k = 0; k < PT; ++k) {
        int idx = t * PT + k;
        if (idx < nb) { bbase[idx] = run; bcur[idx] = run; }
        run += vals[k];
    }
    if (t == 255) bbase[nb] = sd[255];   // total == EE
}

// ---------------- bin edges into bucket-grouped ebuf -----------------------
// Per-tile LDS histogram -> one global atomicAdd per (bucket,tile) chunk ->
// chunk-local writes (line-combining).  Entry = (src<<6) | local_dst.

__global__ __launch_bounds__(256) void k_bin(const int* __restrict__ src,
                                             const int* __restrict__ dst,
                                             int* __restrict__ bcur,
                                             int* __restrict__ ebuf, int E) {
    constexpr int K = TILE / 256;  // 16 edges per thread
    __shared__ int lcnt[NB];
    __shared__ int lbase[NB];
    const int t = threadIdx.x;
    const int e0 = blockIdx.x * TILE;

    for (int i = t; i < NB; i += 256) lcnt[i] = 0;
    __syncthreads();

    int dreg[K], ofs[K];
#pragma unroll
    for (int k = 0; k < K; ++k) {
        int e = e0 + k * 256 + t;
        if (e < E) {
            int d = dst[e];
            dreg[k] = d;
            ofs[k] = atomicAdd(&lcnt[d >> 6], 1);
        } else dreg[k] = -1;
    }
    __syncthreads();

    for (int i = t; i < NB; i += 256) {
        int c = lcnt[i];
        lbase[i] = c ? atomicAdd(&bcur[i], c) : 0;
    }
    __syncthreads();

#pragma unroll
    for (int k = 0; k < K; ++k) {
        if (dreg[k] >= 0) {
            int e = e0 + k * 256 + t;
            int s = src[e];
            int b = dreg[k] >> 6;
            ebuf[lbase[b] + ofs[k]] = (s << 6) | (dreg[k] & 63);
        }
    }
}

// ---------------- fp32 GEMM with fused row scale: G = (X @ W) * dinv[row] ---

template<int NC, int RPT>
__global__ __launch_bounds__(256) void k_gemm(const float* __restrict__ X,
                                              const float* __restrict__ W,
                                              const float* __restrict__ dinv,
                                              float* __restrict__ G, int M) {
    constexpr int CT = NC / 4;
    constexpr int RG = 256 / CT;
    constexpr int TM = RG * RPT;      // 64
    __shared__ float xs[TM * 128];
    const int t = threadIdx.x;
    const int row0 = blockIdx.x * TM;

    for (int idx = t; idx < TM * 32; idx += 256) {
        int r = idx >> 5, c = idx & 31;
        float4 v = make_float4(0.f, 0.f, 0.f, 0.f);
        if (row0 + r < M) v = ((const float4*)(X + (size_t)(row0 + r) * 128))[c];
        ((float4*)xs)[idx] = v;
    }
    __syncthreads();

    const int tc = t % CT;
    const int tr = t / CT;
    float acc[RPT][4];
#pragma unroll
    for (int i = 0; i < RPT; ++i) {
        acc[i][0] = 0.f; acc[i][1] = 0.f; acc[i][2] = 0.f; acc[i][3] = 0.f;
    }
    const float4* __restrict__ Wv = (const float4*)W;
#pragma unroll 4
    for (int k = 0; k < 128; k += 4) {
        float4 w0 = Wv[(k + 0) * CT + tc];
        float4 w1 = Wv[(k + 1) * CT + tc];
        float4 w2 = Wv[(k + 2) * CT + tc];
        float4 w3 = Wv[(k + 3) * CT + tc];
#pragma unroll
        for (int rr = 0; rr < RPT; ++rr) {
            const float4 xv = *((const float4*)(xs + (tr * RPT + rr) * 128 + k));
            acc[rr][0] = fmaf(xv.x, w0.x, fmaf(xv.y, w1.x, fmaf(xv.z, w2.x, fmaf(xv.w, w3.x, acc[rr][0]))));
            acc[rr][1] = fmaf(xv.x, w0.y, fmaf(xv.y, w1.y, fmaf(xv.z, w2.y, fmaf(xv.w, w3.y, acc[rr][1]))));
            acc[rr][2] = fmaf(xv.x, w0.z, fmaf(xv.y, w1.z, fmaf(xv.z, w2.z, fmaf(xv.w, w3.z, acc[rr][2]))));
            acc[rr][3] = fmaf(xv.x, w0.w, fmaf(xv.y, w1.w, fmaf(xv.z, w2.w, fmaf(xv.w, w3.w, acc[rr][3]))));
        }
    }
#pragma unroll
    for (int rr = 0; rr < RPT; ++rr) {
        int r = row0 + tr * RPT + rr;
        if (r < M) {
            float s = dinv[r];
            ((float4*)(G + (size_t)r * NC))[tc] =
                make_float4(acc[rr][0] * s, acc[rr][1] * s, acc[rr][2] * s, acc[rr][3] * s);
        }
    }
}

// ---------------- bucket aggregation in LDS + fused epilogue ---------------
// One block per 64-node bucket.  acc[64][D] in LDS; edges applied with
// ds_add_f32 (bank = lane%32 -> 2-way aliasing, free).  Then
// OUT = dinv[node]*(acc + g[node]) + bias (+relu).

template<int D, bool RELU>
__global__ __launch_bounds__(256) void k_agg(const int* __restrict__ bbase,
                                             const int* __restrict__ ebuf,
                                             const float* __restrict__ G,
                                             const float* __restrict__ dinv,
                                             const float* __restrict__ bias,
                                             float* __restrict__ OUT, int n) {
    __shared__ __align__(16) float acc[BSZ * D];
    const int t = threadIdx.x;
    const int b = blockIdx.x;
    const int node0 = b * BSZ;

    for (int i = t; i < BSZ * D / 4; i += 256)
        ((float4*)acc)[i] = make_float4(0.f, 0.f, 0.f, 0.f);
    __syncthreads();

    const int beg = bbase[b];
    const int end = bbase[b + 1];
    const int w = t >> 6;
    const int lane = t & 63;

    // 2 edges per wave per iteration for memory-level parallelism
    for (int j = beg + 2 * w; j < end; j += 8) {
        int e0 = ebuf[j];
        bool has1 = (j + 1) < end;
        int e1 = has1 ? ebuf[j + 1] : e0;
        int s0 = e0 >> 6, ld0 = e0 & 63;
        int s1 = e1 >> 6, ld1 = e1 & 63;
        if constexpr (D == 128) {
            float v00 = G[(size_t)s0 * 128 + lane];
            float v01 = G[(size_t)s0 * 128 + 64 + lane];
            float v10 = G[(size_t)s1 * 128 + lane];
            float v11 = G[(size_t)s1 * 128 + 64 + lane];
            atomicAdd(&acc[ld0 * 128 + lane], v00);
            atomicAdd(&acc[ld0 * 128 + 64 + lane], v01);
            if (has1) {
                atomicAdd(&acc[ld1 * 128 + lane], v10);
                atomicAdd(&acc[ld1 * 128 + 64 + lane], v11);
            }
        } else {
            float v0 = G[(size_t)s0 * 64 + lane];
            float v1 = G[(size_t)s1 * 64 + lane];
            atomicAdd(&acc[ld0 * 64 + lane], v0);
            if (has1) atomicAdd(&acc[ld1 * 64 + lane], v1);
        }
    }
    __syncthreads();

    constexpr int C = D / 4;
    for (int idx = t; idx < BSZ * C; idx += 256) {
        int nl = idx / C, c = idx % C;
        int node = node0 + nl;
        if (node < n) {
            float di = dinv[node];
            float4 a = ((const float4*)acc)[idx];
            float4 g = ((const float4*)G)[(size_t)node * C + c];
            float4 bv = ((const float4*)bias)[c];
            float4 r;
            r.x = fmaf(a.x + g.x, di, bv.x);
            r.y = fmaf(a.y + g.y, di, bv.y);
            r.z = fmaf(a.z + g.z, di, bv.z);
            r.w = fmaf(a.w + g.w, di, bv.w);
            if (RELU) {
                r.x = fmaxf(r.x, 0.f); r.y = fmaxf(r.y, 0.f);
                r.z = fmaxf(r.z, 0.f); r.w = fmaxf(r.w, 0.f);
            }
            ((float4*)OUT)[(size_t)node * C + c] = r;
        }
    }
}

// ---------------- launch ----------------

extern "C" void kernel_launch(void* const* d_in, const int* in_sizes, int n_in,
                              void* d_out, int out_size, void* d_ws, size_t ws_size,
                              hipStream_t stream) {
    const float* x  = (const float*)d_in[0];
    const float* W1 = (const float*)d_in[1];
    const float* b1 = (const float*)d_in[2];
    const float* W2 = (const float*)d_in[3];
    const float* b2 = (const float*)d_in[4];
    const int*   ei = (const int*)d_in[5];   // [2, E] int32
    const int* src = ei;
    const int* dst = ei + EE;
    float* out = (float*)d_out;

    // ws: cnt N | dinv N | bcnt NB | bbase NB+1 | bcur NB | ebuf E
    //     g1 N*128 | h1r N*128 ; g2 overlays g1 (dead after agg1 epilogue)
    int*   cnt   = (int*)d_ws;                       // N
    float* dinv  = (float*)d_ws + NN;                // N
    int*   bcnt  = (int*)d_ws + 2 * NN;              // NB
    int*   bbase = bcnt + NB;                        // NB+1
    int*   bcur  = bbase + NB + 1;                   // NB
    int*   ebuf  = bcur + NB;                        // E
    float* g1    = (float*)(ebuf + EE);              // N*128
    float* h1r   = g1 + (size_t)NN * 128;            // N*128
    float* g2    = g1;                               // N*64 (reuse)

    hipMemsetAsync(cnt, 0, NN * sizeof(int), stream);
    k_count<<<(EE + 255) / 256, 256, 0, stream>>>(dst, cnt, EE);
    k_dinv<<<(NN + 255) / 256, 256, 0, stream>>>(cnt, dinv, NN);
    k_bsum<<<(NB + 3) / 4, 256, 0, stream>>>(cnt, bcnt, NN, NB);
    k_scanb<<<1, 256, 0, stream>>>(bcnt, bbase, bcur, NB);
    k_bin<<<(EE + TILE - 1) / TILE, 256, 0, stream>>>(src, dst, bcur, ebuf, EE);

    // layer 1: g1 = (x@W1)*dinv ; h1r = relu(dinv*(agg+g1) + b1)
    k_gemm<128, 8><<<(NN + 63) / 64, 256, 0, stream>>>(x, W1, dinv, g1, NN);
    k_agg<128, true><<<NB, 256, 0, stream>>>(bbase, ebuf, g1, dinv, b1, h1r, NN);

    // layer 2: g2 = (h1r@W2)*dinv ; out = dinv*(agg+g2) + b2
    k_gemm<64, 4><<<(NN + 63) / 64, 256, 0, stream>>>(h1r, W2, dinv, g2, NN);
    k_agg<64, false><<<NB, 256, 0, stream>>>(bbase, ebuf, g2, dinv, b2, out, NN);
}

// Round 4
// 544.870 us; speedup vs baseline: 3.8095x; 3.8095x over previous
//
#include <hip/hip_runtime.h>

static constexpr int NN = 100000;    // nodes
static constexpr int EE = 1600000;   // edges (before self-loops)
static constexpr int BSZ = 64;       // nodes per bucket
static constexpr int NB = (NN + BSZ - 1) / BSZ;   // 1563 buckets
static constexpr int TILE = 4096;    // edges per k_bin block
static constexpr int NCH = (NN + 511) / 512;      // node-scan chunks

// ---------------- degree histogram / dinv ----------------

__global__ __launch_bounds__(256) void k_count(const int* __restrict__ dst,
                                               int* __restrict__ cnt, int E) {
    int i = blockIdx.x * 256 + threadIdx.x;
    if (i < E) atomicAdd(&cnt[dst[i]], 1);
}

__global__ __launch_bounds__(256) void k_dinv(const int* __restrict__ cnt,
                                              float* __restrict__ dinv, int n) {
    int i = blockIdx.x * 256 + threadIdx.x;
    if (i < n) dinv[i] = rsqrtf((float)cnt[i] + 1.0f);  // +1 self-loop
}

// ---------------- exclusive scan of cnt -> rowptr (3-phase) ----------------

__global__ __launch_bounds__(256) void k_scan1(const int* __restrict__ cnt,
                                               int* __restrict__ rowptr,
                                               int* __restrict__ csum, int n) {
    __shared__ int sd[256];
    const int c = blockIdx.x, t = threadIdx.x;
    const int i0 = c * 512 + t * 2;
    int a0 = (i0 < n) ? cnt[i0] : 0;
    int a1 = (i0 + 1 < n) ? cnt[i0 + 1] : 0;
    sd[t] = a0 + a1;
    __syncthreads();
    for (int off = 1; off < 256; off <<= 1) {
        int v = (t >= off) ? sd[t - off] : 0;
        __syncthreads();
        sd[t] += v;
        __syncthreads();
    }
    int exc = (t == 0) ? 0 : sd[t - 1];
    if (i0 < n) rowptr[i0] = exc;
    if (i0 + 1 < n) rowptr[i0 + 1] = exc + a0;
    if (t == 255) csum[c] = sd[255];
}

__global__ __launch_bounds__(256) void k_scan2(int* __restrict__ csum, int m) {
    __shared__ int sd[256];
    const int t = threadIdx.x;
    sd[t] = (t < m) ? csum[t] : 0;
    __syncthreads();
    for (int off = 1; off < 256; off <<= 1) {
        int v = (t >= off) ? sd[t - off] : 0;
        __syncthreads();
        sd[t] += v;
        __syncthreads();
    }
    if (t < m) csum[t] = (t == 0) ? 0 : sd[t - 1];
}

__global__ __launch_bounds__(256) void k_scan3(int* __restrict__ rowptr,
                                               const int* __restrict__ csum, int n) {
    int i = blockIdx.x * 256 + threadIdx.x;
    if (i < n) rowptr[i] += csum[i >> 9];
}

// ---------------- bucket counts + bucket scan ------------------------------

__global__ __launch_bounds__(256) void k_bsum(const int* __restrict__ cnt,
                                              int* __restrict__ bcnt, int n, int nb) {
    const int b = blockIdx.x * 4 + (threadIdx.x >> 6);
    const int lane = threadIdx.x & 63;
    if (b >= nb) return;
    const int node = b * BSZ + lane;
    int v = (node < n) ? cnt[node] : 0;
#pragma unroll
    for (int m = 32; m >= 1; m >>= 1) v += __shfl_xor(v, m, 64);
    if (lane == 0) bcnt[b] = v;
}

__global__ __launch_bounds__(256) void k_scanb(const int* __restrict__ bcnt,
                                               int* __restrict__ bbase,
                                               int* __restrict__ bcur, int nb) {
    constexpr int PT = 7;  // 256*7 = 1792 >= NB
    __shared__ int sd[256];
    const int t = threadIdx.x;
    int vals[PT];
    int s = 0;
#pragma unroll
    for (int k = 0; k < PT; ++k) {
        int idx = t * PT + k;
        vals[k] = (idx < nb) ? bcnt[idx] : 0;
        s += vals[k];
    }
    sd[t] = s;
    __syncthreads();
    for (int off = 1; off < 256; off <<= 1) {
        int v = (t >= off) ? sd[t - off] : 0;
        __syncthreads();
        sd[t] += v;
        __syncthreads();
    }
    int run = (t == 0) ? 0 : sd[t - 1];
#pragma unroll
    for (int k = 0; k < PT; ++k) {
        int idx = t * PT + k;
        if (idx < nb) { bbase[idx] = run; bcur[idx] = run; }
        run += vals[k];
    }
    if (t == 255) bbase[nb] = sd[255];   // == EE
}

// ---------------- bin edges into bucket-grouped ebuf (line-combining) ------
// Entry = (src<<6) | local_dst.

__global__ __launch_bounds__(256) void k_bin(const int* __restrict__ src,
                                             const int* __restrict__ dst,
                                             int* __restrict__ bcur,
                                             int* __restrict__ ebuf, int E) {
    constexpr int K = TILE / 256;  // 16 edges per thread
    __shared__ int lcnt[NB];
    __shared__ int lbase[NB];
    const int t = threadIdx.x;
    const int e0 = blockIdx.x * TILE;

    for (int i = t; i < NB; i += 256) lcnt[i] = 0;
    __syncthreads();

    int dreg[K], ofs[K];
#pragma unroll
    for (int k = 0; k < K; ++k) {
        int e = e0 + k * 256 + t;
        if (e < E) {
            int d = dst[e];
            dreg[k] = d;
            ofs[k] = atomicAdd(&lcnt[d >> 6], 1);
        } else dreg[k] = -1;
    }
    __syncthreads();

    for (int i = t; i < NB; i += 256) {
        int c = lcnt[i];
        lbase[i] = c ? atomicAdd(&bcur[i], c) : 0;
    }
    __syncthreads();

#pragma unroll
    for (int k = 0; k < K; ++k) {
        if (dreg[k] >= 0) {
            int e = e0 + k * 256 + t;
            int s = src[e];
            int b = dreg[k] >> 6;
            ebuf[lbase[b] + ofs[k]] = (s << 6) | (dreg[k] & 63);
        }
    }
}

// ---------------- bucket-grouped ebuf -> per-node CSR ----------------------
// One block per bucket; writes land in the bucket's ~4KB window (combining).

__global__ __launch_bounds__(256) void k_csr(const int* __restrict__ bbase,
                                             const int* __restrict__ ebuf,
                                             const int* __restrict__ rowptr,
                                             int* __restrict__ csr, int n) {
    __shared__ int lofs[BSZ];
    const int b = blockIdx.x, t = threadIdx.x;
    if (t < BSZ) {
        int node = b * BSZ + t;
        lofs[t] = (node < n) ? rowptr[node] : 0;
    }
    __syncthreads();
    const int beg = bbase[b], end = bbase[b + 1];
    for (int j = beg + t; j < end; j += 256) {
        int e = ebuf[j];
        int pos = atomicAdd(&lofs[e & 63], 1);
        csr[pos] = e >> 6;
    }
}

// ---------------- fp32 GEMM with fused row scale: G = (X @ W) * dinv[row] ---

template<int NC, int RPT>
__global__ __launch_bounds__(256) void k_gemm(const float* __restrict__ X,
                                              const float* __restrict__ W,
                                              const float* __restrict__ dinv,
                                              float* __restrict__ G, int M) {
    constexpr int CT = NC / 4;
    constexpr int RG = 256 / CT;
    constexpr int TM = RG * RPT;      // 64
    __shared__ float xs[TM * 128];
    const int t = threadIdx.x;
    const int row0 = blockIdx.x * TM;

    for (int idx = t; idx < TM * 32; idx += 256) {
        int r = idx >> 5, c = idx & 31;
        float4 v = make_float4(0.f, 0.f, 0.f, 0.f);
        if (row0 + r < M) v = ((const float4*)(X + (size_t)(row0 + r) * 128))[c];
        ((float4*)xs)[idx] = v;
    }
    __syncthreads();

    const int tc = t % CT;
    const int tr = t / CT;
    float acc[RPT][4];
#pragma unroll
    for (int i = 0; i < RPT; ++i) {
        acc[i][0] = 0.f; acc[i][1] = 0.f; acc[i][2] = 0.f; acc[i][3] = 0.f;
    }
    const float4* __restrict__ Wv = (const float4*)W;
#pragma unroll 4
    for (int k = 0; k < 128; k += 4) {
        float4 w0 = Wv[(k + 0) * CT + tc];
        float4 w1 = Wv[(k + 1) * CT + tc];
        float4 w2 = Wv[(k + 2) * CT + tc];
        float4 w3 = Wv[(k + 3) * CT + tc];
#pragma unroll
        for (int rr = 0; rr < RPT; ++rr) {
            const float4 xv = *((const float4*)(xs + (tr * RPT + rr) * 128 + k));
            acc[rr][0] = fmaf(xv.x, w0.x, fmaf(xv.y, w1.x, fmaf(xv.z, w2.x, fmaf(xv.w, w3.x, acc[rr][0]))));
            acc[rr][1] = fmaf(xv.x, w0.y, fmaf(xv.y, w1.y, fmaf(xv.z, w2.y, fmaf(xv.w, w3.y, acc[rr][1]))));
            acc[rr][2] = fmaf(xv.x, w0.z, fmaf(xv.y, w1.z, fmaf(xv.z, w2.z, fmaf(xv.w, w3.z, acc[rr][2]))));
            acc[rr][3] = fmaf(xv.x, w0.w, fmaf(xv.y, w1.w, fmaf(xv.z, w2.w, fmaf(xv.w, w3.w, acc[rr][3]))));
        }
    }
#pragma unroll
    for (int rr = 0; rr < RPT; ++rr) {
        int r = row0 + tr * RPT + rr;
        if (r < M) {
            float s = dinv[r];
            ((float4*)(G + (size_t)r * NC))[tc] =
                make_float4(acc[rr][0] * s, acc[rr][1] * s, acc[rr][2] * s, acc[rr][3] * s);
        }
    }
}

// ---------------- gather + fused epilogue ----------------------------------
// Wave per node: OUT[i] = dinv[i]*(sum_{s in N(i)} g[s] + g[i]) + bias (+relu)
// 4-edge unroll for memory-level parallelism.

template<bool RELU>
__global__ __launch_bounds__(256) void k_gather128(const int* __restrict__ rowptr,
                                                   const int* __restrict__ csr,
                                                   const float* __restrict__ G,
                                                   const float* __restrict__ dinv,
                                                   const float* __restrict__ bias,
                                                   float* __restrict__ OUT,
                                                   int n, int E) {
    const int node = blockIdx.x * 4 + (threadIdx.x >> 6);
    if (node >= n) return;
    const int lane = threadIdx.x & 63;
    const int beg = rowptr[node];
    const int end = (node == n - 1) ? E : rowptr[node + 1];

    const float2* __restrict__ Gv = (const float2*)G;
    float2 a0 = make_float2(0.f, 0.f), a1 = make_float2(0.f, 0.f);
    float2 a2 = make_float2(0.f, 0.f), a3 = make_float2(0.f, 0.f);
    int j = beg;
    for (; j + 4 <= end; j += 4) {
        int s0 = csr[j], s1 = csr[j + 1], s2 = csr[j + 2], s3 = csr[j + 3];
        float2 v0 = Gv[(size_t)s0 * 64 + lane];
        float2 v1 = Gv[(size_t)s1 * 64 + lane];
        float2 v2 = Gv[(size_t)s2 * 64 + lane];
        float2 v3 = Gv[(size_t)s3 * 64 + lane];
        a0.x += v0.x; a0.y += v0.y;
        a1.x += v1.x; a1.y += v1.y;
        a2.x += v2.x; a2.y += v2.y;
        a3.x += v3.x; a3.y += v3.y;
    }
    for (; j < end; ++j) {
        float2 v = Gv[(size_t)csr[j] * 64 + lane];
        a0.x += v.x; a0.y += v.y;
    }
    float2 g = Gv[(size_t)node * 64 + lane];     // self-loop term
    float sx = a0.x + a1.x + a2.x + a3.x + g.x;
    float sy = a0.y + a1.y + a2.y + a3.y + g.y;
    float di = dinv[node];
    float2 bv = ((const float2*)bias)[lane];
    float2 r;
    r.x = fmaf(sx, di, bv.x);
    r.y = fmaf(sy, di, bv.y);
    if (RELU) { r.x = fmaxf(r.x, 0.f); r.y = fmaxf(r.y, 0.f); }
    ((float2*)OUT)[(size_t)node * 64 + lane] = r;
}

template<bool RELU>
__global__ __launch_bounds__(256) void k_gather64(const int* __restrict__ rowptr,
                                                  const int* __restrict__ csr,
                                                  const float* __restrict__ G,
                                                  const float* __restrict__ dinv,
                                                  const float* __restrict__ bias,
                                                  float* __restrict__ OUT,
                                                  int n, int E) {
    const int node = blockIdx.x * 4 + (threadIdx.x >> 6);
    if (node >= n) return;
    const int lane = threadIdx.x & 63;
    const int beg = rowptr[node];
    const int end = (node == n - 1) ? E : rowptr[node + 1];

    float a0 = 0.f, a1 = 0.f, a2 = 0.f, a3 = 0.f;
    int j = beg;
    for (; j + 4 <= end; j += 4) {
        int s0 = csr[j], s1 = csr[j + 1], s2 = csr[j + 2], s3 = csr[j + 3];
        a0 += G[(size_t)s0 * 64 + lane];
        a1 += G[(size_t)s1 * 64 + lane];
        a2 += G[(size_t)s2 * 64 + lane];
        a3 += G[(size_t)s3 * 64 + lane];
    }
    for (; j < end; ++j) a0 += G[(size_t)csr[j] * 64 + lane];
    float s = a0 + a1 + a2 + a3 + G[(size_t)node * 64 + lane];
    float r = fmaf(s, dinv[node], bias[lane]);
    if (RELU) r = fmaxf(r, 0.f);
    OUT[(size_t)node * 64 + lane] = r;
}

// ---------------- launch ----------------

extern "C" void kernel_launch(void* const* d_in, const int* in_sizes, int n_in,
                              void* d_out, int out_size, void* d_ws, size_t ws_size,
                              hipStream_t stream) {
    const float* x  = (const float*)d_in[0];
    const float* W1 = (const float*)d_in[1];
    const float* b1 = (const float*)d_in[2];
    const float* W2 = (const float*)d_in[3];
    const float* b2 = (const float*)d_in[4];
    const int*   ei = (const int*)d_in[5];   // [2, E] int32
    const int* src = ei;
    const int* dst = ei + EE;
    float* out = (float*)d_out;

    // ws: cnt N | dinv N | rowptr N | csum 256 | bcnt NB | bbase NB+1 | bcur NB
    //     csr E | g1 N*128 | h1r N*128
    // ebuf overlays h1r (dead before gather1 writes h1r); g2 overlays g1.
    int*   cnt    = (int*)d_ws;                  // N
    float* dinv   = (float*)d_ws + NN;           // N
    int*   rowptr = (int*)d_ws + 2 * NN;         // N
    int*   csum   = (int*)d_ws + 3 * NN;         // 256
    int*   bcnt   = csum + 256;                  // NB
    int*   bbase  = bcnt + NB;                   // NB+1
    int*   bcur   = bbase + NB + 1;              // NB
    int*   csr    = bcur + NB;                   // E
    float* g1     = (float*)(csr + EE);          // N*128
    float* h1r    = g1 + (size_t)NN * 128;       // N*128
    int*   ebuf   = (int*)h1r;                   // E (overlay)
    float* g2     = g1;                          // N*64 (reuse)

    hipMemsetAsync(cnt, 0, NN * sizeof(int), stream);
    k_count<<<(EE + 255) / 256, 256, 0, stream>>>(dst, cnt, EE);
    k_dinv<<<(NN + 255) / 256, 256, 0, stream>>>(cnt, dinv, NN);
    k_scan1<<<NCH, 256, 0, stream>>>(cnt, rowptr, csum, NN);
    k_scan2<<<1, 256, 0, stream>>>(csum, NCH);
    k_scan3<<<(NN + 255) / 256, 256, 0, stream>>>(rowptr, csum, NN);
    k_bsum<<<(NB + 3) / 4, 256, 0, stream>>>(cnt, bcnt, NN, NB);
    k_scanb<<<1, 256, 0, stream>>>(bcnt, bbase, bcur, NB);
    k_bin<<<(EE + TILE - 1) / TILE, 256, 0, stream>>>(src, dst, bcur, ebuf, EE);
    k_csr<<<NB, 256, 0, stream>>>(bbase, ebuf, rowptr, csr, NN);

    // layer 1: g1 = (x@W1)*dinv ; h1r = relu(dinv*(agg+g1) + b1)
    k_gemm<128, 8><<<(NN + 63) / 64, 256, 0, stream>>>(x, W1, dinv, g1, NN);
    k_gather128<true><<<(NN + 3) / 4, 256, 0, stream>>>(rowptr, csr, g1, dinv, b1, h1r, NN, EE);

    // layer 2: g2 = (h1r@W2)*dinv ; out = dinv*(agg+g2) + b2
    k_gemm<64, 4><<<(NN + 63) / 64, 256, 0, stream>>>(h1r, W2, dinv, g2, NN);
    k_gather64<false><<<(NN + 3) / 4, 256, 0, stream>>>(rowptr, csr, g2, dinv, b2, out, NN, EE);
}

// Round 5
// 495.555 us; speedup vs baseline: 4.1886x; 1.0995x over previous
//
#include <hip/hip_runtime.h>

static constexpr int NN = 100000;    // nodes
static constexpr int EE = 1600000;   // edges (before self-loops)
static constexpr int BSZ = 64;       // nodes per bucket
static constexpr int NB = (NN + BSZ - 1) / BSZ;   // 1563 buckets
static constexpr int TILE = 4096;    // edges per k_bin block
static constexpr int NCH = (NN + 511) / 512;      // node-scan chunks

// ---- bf16 helpers (manual bit twiddling; storage-only, math stays fp32) ----

__device__ __forceinline__ unsigned short f2bf(float f) {   // round-to-nearest-even
    unsigned u = __float_as_uint(f);
    u += 0x7FFFu + ((u >> 16) & 1u);
    return (unsigned short)(u >> 16);
}
__device__ __forceinline__ float bfl(unsigned u) { return __uint_as_float(u << 16); }
__device__ __forceinline__ float bfh(unsigned u) { return __uint_as_float(u & 0xFFFF0000u); }
__device__ __forceinline__ float bfs(unsigned short s) { return __uint_as_float(((unsigned)s) << 16); }

// ---------------- degree histogram / dinv ----------------

__global__ __launch_bounds__(256) void k_count(const int* __restrict__ dst,
                                               int* __restrict__ cnt, int E) {
    int i = blockIdx.x * 256 + threadIdx.x;
    if (i < E) atomicAdd(&cnt[dst[i]], 1);
}

__global__ __launch_bounds__(256) void k_dinv(const int* __restrict__ cnt,
                                              float* __restrict__ dinv, int n) {
    int i = blockIdx.x * 256 + threadIdx.x;
    if (i < n) dinv[i] = rsqrtf((float)cnt[i] + 1.0f);  // +1 self-loop
}

// ---------------- exclusive scan of cnt -> rowptr (3-phase) ----------------

__global__ __launch_bounds__(256) void k_scan1(const int* __restrict__ cnt,
                                               int* __restrict__ rowptr,
                                               int* __restrict__ csum, int n) {
    __shared__ int sd[256];
    const int c = blockIdx.x, t = threadIdx.x;
    const int i0 = c * 512 + t * 2;
    int a0 = (i0 < n) ? cnt[i0] : 0;
    int a1 = (i0 + 1 < n) ? cnt[i0 + 1] : 0;
    sd[t] = a0 + a1;
    __syncthreads();
    for (int off = 1; off < 256; off <<= 1) {
        int v = (t >= off) ? sd[t - off] : 0;
        __syncthreads();
        sd[t] += v;
        __syncthreads();
    }
    int exc = (t == 0) ? 0 : sd[t - 1];
    if (i0 < n) rowptr[i0] = exc;
    if (i0 + 1 < n) rowptr[i0 + 1] = exc + a0;
    if (t == 255) csum[c] = sd[255];
}

__global__ __launch_bounds__(256) void k_scan2(int* __restrict__ csum, int m) {
    __shared__ int sd[256];
    const int t = threadIdx.x;
    sd[t] = (t < m) ? csum[t] : 0;
    __syncthreads();
    for (int off = 1; off < 256; off <<= 1) {
        int v = (t >= off) ? sd[t - off] : 0;
        __syncthreads();
        sd[t] += v;
        __syncthreads();
    }
    if (t < m) csum[t] = (t == 0) ? 0 : sd[t - 1];
}

__global__ __launch_bounds__(256) void k_scan3(int* __restrict__ rowptr,
                                               const int* __restrict__ csum, int n) {
    int i = blockIdx.x * 256 + threadIdx.x;
    if (i < n) rowptr[i] += csum[i >> 9];
}

// ---------------- bucket counts + bucket scan ------------------------------

__global__ __launch_bounds__(256) void k_bsum(const int* __restrict__ cnt,
                                              int* __restrict__ bcnt, int n, int nb) {
    const int b = blockIdx.x * 4 + (threadIdx.x >> 6);
    const int lane = threadIdx.x & 63;
    if (b >= nb) return;
    const int node = b * BSZ + lane;
    int v = (node < n) ? cnt[node] : 0;
#pragma unroll
    for (int m = 32; m >= 1; m >>= 1) v += __shfl_xor(v, m, 64);
    if (lane == 0) bcnt[b] = v;
}

__global__ __launch_bounds__(256) void k_scanb(const int* __restrict__ bcnt,
                                               int* __restrict__ bbase,
                                               int* __restrict__ bcur, int nb) {
    constexpr int PT = 7;  // 256*7 = 1792 >= NB
    __shared__ int sd[256];
    const int t = threadIdx.x;
    int vals[PT];
    int s = 0;
#pragma unroll
    for (int k = 0; k < PT; ++k) {
        int idx = t * PT + k;
        vals[k] = (idx < nb) ? bcnt[idx] : 0;
        s += vals[k];
    }
    sd[t] = s;
    __syncthreads();
    for (int off = 1; off < 256; off <<= 1) {
        int v = (t >= off) ? sd[t - off] : 0;
        __syncthreads();
        sd[t] += v;
        __syncthreads();
    }
    int run = (t == 0) ? 0 : sd[t - 1];
#pragma unroll
    for (int k = 0; k < PT; ++k) {
        int idx = t * PT + k;
        if (idx < nb) { bbase[idx] = run; bcur[idx] = run; }
        run += vals[k];
    }
    if (t == 255) bbase[nb] = sd[255];   // == EE
}

// ---------------- bin edges into bucket-grouped ebuf (line-combining) ------
// Entry = (src<<6) | local_dst.

__global__ __launch_bounds__(256) void k_bin(const int* __restrict__ src,
                                             const int* __restrict__ dst,
                                             int* __restrict__ bcur,
                                             int* __restrict__ ebuf, int E) {
    constexpr int K = TILE / 256;  // 16 edges per thread
    __shared__ int lcnt[NB];
    __shared__ int lbase[NB];
    const int t = threadIdx.x;
    const int e0 = blockIdx.x * TILE;

    for (int i = t; i < NB; i += 256) lcnt[i] = 0;
    __syncthreads();

    int dreg[K], ofs[K];
#pragma unroll
    for (int k = 0; k < K; ++k) {
        int e = e0 + k * 256 + t;
        if (e < E) {
            int d = dst[e];
            dreg[k] = d;
            ofs[k] = atomicAdd(&lcnt[d >> 6], 1);
        } else dreg[k] = -1;
    }
    __syncthreads();

    for (int i = t; i < NB; i += 256) {
        int c = lcnt[i];
        lbase[i] = c ? atomicAdd(&bcur[i], c) : 0;
    }
    __syncthreads();

#pragma unroll
    for (int k = 0; k < K; ++k) {
        if (dreg[k] >= 0) {
            int e = e0 + k * 256 + t;
            int s = src[e];
            int b = dreg[k] >> 6;
            ebuf[lbase[b] + ofs[k]] = (s << 6) | (dreg[k] & 63);
        }
    }
}

// ---------------- bucket-grouped ebuf -> per-node CSR ----------------------

__global__ __launch_bounds__(256) void k_csr(const int* __restrict__ bbase,
                                             const int* __restrict__ ebuf,
                                             const int* __restrict__ rowptr,
                                             int* __restrict__ csr, int n) {
    __shared__ int lofs[BSZ];
    const int b = blockIdx.x, t = threadIdx.x;
    if (t < BSZ) {
        int node = b * BSZ + t;
        lofs[t] = (node < n) ? rowptr[node] : 0;
    }
    __syncthreads();
    const int beg = bbase[b], end = bbase[b + 1];
    for (int j = beg + t; j < end; j += 256) {
        int e = ebuf[j];
        int pos = atomicAdd(&lofs[e & 63], 1);
        csr[pos] = e >> 6;
    }
}

// ---------------- fp32 GEMM, bf16 output: G = bf16((X @ W) * dinv[row]) ----

template<int NC, int RPT>
__global__ __launch_bounds__(256) void k_gemm(const float* __restrict__ X,
                                              const float* __restrict__ W,
                                              const float* __restrict__ dinv,
                                              unsigned short* __restrict__ G, int M) {
    constexpr int CT = NC / 4;
    constexpr int RG = 256 / CT;
    constexpr int TM = RG * RPT;      // 64
    __shared__ float xs[TM * 128];
    const int t = threadIdx.x;
    const int row0 = blockIdx.x * TM;

    for (int idx = t; idx < TM * 32; idx += 256) {
        int r = idx >> 5, c = idx & 31;
        float4 v = make_float4(0.f, 0.f, 0.f, 0.f);
        if (row0 + r < M) v = ((const float4*)(X + (size_t)(row0 + r) * 128))[c];
        ((float4*)xs)[idx] = v;
    }
    __syncthreads();

    const int tc = t % CT;
    const int tr = t / CT;
    float acc[RPT][4];
#pragma unroll
    for (int i = 0; i < RPT; ++i) {
        acc[i][0] = 0.f; acc[i][1] = 0.f; acc[i][2] = 0.f; acc[i][3] = 0.f;
    }
    const float4* __restrict__ Wv = (const float4*)W;
#pragma unroll 4
    for (int k = 0; k < 128; k += 4) {
        float4 w0 = Wv[(k + 0) * CT + tc];
        float4 w1 = Wv[(k + 1) * CT + tc];
        float4 w2 = Wv[(k + 2) * CT + tc];
        float4 w3 = Wv[(k + 3) * CT + tc];
#pragma unroll
        for (int rr = 0; rr < RPT; ++rr) {
            const float4 xv = *((const float4*)(xs + (tr * RPT + rr) * 128 + k));
            acc[rr][0] = fmaf(xv.x, w0.x, fmaf(xv.y, w1.x, fmaf(xv.z, w2.x, fmaf(xv.w, w3.x, acc[rr][0]))));
            acc[rr][1] = fmaf(xv.x, w0.y, fmaf(xv.y, w1.y, fmaf(xv.z, w2.y, fmaf(xv.w, w3.y, acc[rr][1]))));
            acc[rr][2] = fmaf(xv.x, w0.z, fmaf(xv.y, w1.z, fmaf(xv.z, w2.z, fmaf(xv.w, w3.z, acc[rr][2]))));
            acc[rr][3] = fmaf(xv.x, w0.w, fmaf(xv.y, w1.w, fmaf(xv.z, w2.w, fmaf(xv.w, w3.w, acc[rr][3]))));
        }
    }
#pragma unroll
    for (int rr = 0; rr < RPT; ++rr) {
        int r = row0 + tr * RPT + rr;
        if (r < M) {
            float s = dinv[r];
            uint2 p;
            p.x = (unsigned)f2bf(acc[rr][0] * s) | ((unsigned)f2bf(acc[rr][1] * s) << 16);
            p.y = (unsigned)f2bf(acc[rr][2] * s) | ((unsigned)f2bf(acc[rr][3] * s) << 16);
            ((uint2*)G)[(size_t)r * (NC / 4) + tc] = p;
        }
    }
}

// ---------------- gather + fused epilogue (bf16 rows, fp32 accumulate) ------
// Wave per node: OUT[i] = dinv[i]*(sum_{s in N(i)} g[s] + g[i]) + bias (+relu)
// 8-edge unroll for memory-level parallelism.

template<bool RELU>
__global__ __launch_bounds__(256) void k_gather128(const int* __restrict__ rowptr,
                                                   const int* __restrict__ csr,
                                                   const unsigned* __restrict__ G,   // bf16x2 per uint, 64/row
                                                   const float* __restrict__ dinv,
                                                   const float* __restrict__ bias,
                                                   float* __restrict__ OUT,
                                                   int n, int E) {
    const int node = blockIdx.x * 4 + (threadIdx.x >> 6);
    if (node >= n) return;
    const int lane = threadIdx.x & 63;
    const int beg = rowptr[node];
    const int end = (node == n - 1) ? E : rowptr[node + 1];

    float ax0 = 0.f, ay0 = 0.f, ax1 = 0.f, ay1 = 0.f;
    float ax2 = 0.f, ay2 = 0.f, ax3 = 0.f, ay3 = 0.f;
    int j = beg;
    for (; j + 8 <= end; j += 8) {
        unsigned u0 = G[(size_t)csr[j + 0] * 64 + lane];
        unsigned u1 = G[(size_t)csr[j + 1] * 64 + lane];
        unsigned u2 = G[(size_t)csr[j + 2] * 64 + lane];
        unsigned u3 = G[(size_t)csr[j + 3] * 64 + lane];
        unsigned u4 = G[(size_t)csr[j + 4] * 64 + lane];
        unsigned u5 = G[(size_t)csr[j + 5] * 64 + lane];
        unsigned u6 = G[(size_t)csr[j + 6] * 64 + lane];
        unsigned u7 = G[(size_t)csr[j + 7] * 64 + lane];
        ax0 += bfl(u0); ay0 += bfh(u0);
        ax1 += bfl(u1); ay1 += bfh(u1);
        ax2 += bfl(u2); ay2 += bfh(u2);
        ax3 += bfl(u3); ay3 += bfh(u3);
        ax0 += bfl(u4); ay0 += bfh(u4);
        ax1 += bfl(u5); ay1 += bfh(u5);
        ax2 += bfl(u6); ay2 += bfh(u6);
        ax3 += bfl(u7); ay3 += bfh(u7);
    }
    for (; j < end; ++j) {
        unsigned u = G[(size_t)csr[j] * 64 + lane];
        ax0 += bfl(u); ay0 += bfh(u);
    }
    unsigned us = G[(size_t)node * 64 + lane];   // self-loop term
    float sx = ax0 + ax1 + ax2 + ax3 + bfl(us);
    float sy = ay0 + ay1 + ay2 + ay3 + bfh(us);
    float di = dinv[node];
    float2 bv = ((const float2*)bias)[lane];
    float2 r;
    r.x = fmaf(sx, di, bv.x);
    r.y = fmaf(sy, di, bv.y);
    if (RELU) { r.x = fmaxf(r.x, 0.f); r.y = fmaxf(r.y, 0.f); }
    ((float2*)OUT)[(size_t)node * 64 + lane] = r;
}

template<bool RELU>
__global__ __launch_bounds__(256) void k_gather64(const int* __restrict__ rowptr,
                                                  const int* __restrict__ csr,
                                                  const unsigned short* __restrict__ G,  // bf16, 64/row
                                                  const float* __restrict__ dinv,
                                                  const float* __restrict__ bias,
                                                  float* __restrict__ OUT,
                                                  int n, int E) {
    const int node = blockIdx.x * 4 + (threadIdx.x >> 6);
    if (node >= n) return;
    const int lane = threadIdx.x & 63;
    const int beg = rowptr[node];
    const int end = (node == n - 1) ? E : rowptr[node + 1];

    float a0 = 0.f, a1 = 0.f, a2 = 0.f, a3 = 0.f;
    int j = beg;
    for (; j + 8 <= end; j += 8) {
        unsigned short s0 = G[(size_t)csr[j + 0] * 64 + lane];
        unsigned short s1 = G[(size_t)csr[j + 1] * 64 + lane];
        unsigned short s2 = G[(size_t)csr[j + 2] * 64 + lane];
        unsigned short s3 = G[(size_t)csr[j + 3] * 64 + lane];
        unsigned short s4 = G[(size_t)csr[j + 4] * 64 + lane];
        unsigned short s5 = G[(size_t)csr[j + 5] * 64 + lane];
        unsigned short s6 = G[(size_t)csr[j + 6] * 64 + lane];
        unsigned short s7 = G[(size_t)csr[j + 7] * 64 + lane];
        a0 += bfs(s0); a1 += bfs(s1); a2 += bfs(s2); a3 += bfs(s3);
        a0 += bfs(s4); a1 += bfs(s5); a2 += bfs(s6); a3 += bfs(s7);
    }
    for (; j < end; ++j) a0 += bfs(G[(size_t)csr[j] * 64 + lane]);
    float s = a0 + a1 + a2 + a3 + bfs(G[(size_t)node * 64 + lane]);
    float r = fmaf(s, dinv[node], bias[lane]);
    if (RELU) r = fmaxf(r, 0.f);
    OUT[(size_t)node * 64 + lane] = r;
}

// ---------------- launch ----------------

extern "C" void kernel_launch(void* const* d_in, const int* in_sizes, int n_in,
                              void* d_out, int out_size, void* d_ws, size_t ws_size,
                              hipStream_t stream) {
    const float* x  = (const float*)d_in[0];
    const float* W1 = (const float*)d_in[1];
    const float* b1 = (const float*)d_in[2];
    const float* W2 = (const float*)d_in[3];
    const float* b2 = (const float*)d_in[4];
    const int*   ei = (const int*)d_in[5];   // [2, E] int32
    const int* src = ei;
    const int* dst = ei + EE;
    float* out = (float*)d_out;

    // ws (flat, 4-byte words):
    // cnt N | dinv N | rowptr N | csum 256 | bcnt NB | bbase NB+1 | bcur NB
    // csr E | ebuf E | g1b N*64 (bf16 N*128) | h1r N*128 f | g2b N*32 (bf16 N*64)
    int*   cnt    = (int*)d_ws;                  // N
    float* dinv   = (float*)d_ws + NN;           // N
    int*   rowptr = (int*)d_ws + 2 * NN;         // N
    int*   csum   = (int*)d_ws + 3 * NN;         // 256
    int*   bcnt   = csum + 256;                  // NB
    int*   bbase  = bcnt + NB;                   // NB+1
    int*   bcur   = bbase + NB + 1;              // NB
    int*   csr    = bcur + NB;                   // E
    int*   ebuf   = csr + EE;                    // E
    unsigned* g1b = (unsigned*)(ebuf + EE);      // N*64 uints = N*128 bf16
    float* h1r    = (float*)(g1b + (size_t)NN * 64);   // N*128 f
    unsigned short* g2b = (unsigned short*)(h1r + (size_t)NN * 128); // N*64 bf16

    hipMemsetAsync(cnt, 0, NN * sizeof(int), stream);
    k_count<<<(EE + 255) / 256, 256, 0, stream>>>(dst, cnt, EE);
    k_dinv<<<(NN + 255) / 256, 256, 0, stream>>>(cnt, dinv, NN);
    k_scan1<<<NCH, 256, 0, stream>>>(cnt, rowptr, csum, NN);
    k_scan2<<<1, 256, 0, stream>>>(csum, NCH);
    k_scan3<<<(NN + 255) / 256, 256, 0, stream>>>(rowptr, csum, NN);
    k_bsum<<<(NB + 3) / 4, 256, 0, stream>>>(cnt, bcnt, NN, NB);
    k_scanb<<<1, 256, 0, stream>>>(bcnt, bbase, bcur, NB);
    k_bin<<<(EE + TILE - 1) / TILE, 256, 0, stream>>>(src, dst, bcur, ebuf, EE);
    k_csr<<<NB, 256, 0, stream>>>(bbase, ebuf, rowptr, csr, NN);

    // layer 1: g1b = bf16((x@W1)*dinv) ; h1r = relu(dinv*(agg+g1) + b1)  [fp32]
    k_gemm<128, 8><<<(NN + 63) / 64, 256, 0, stream>>>(x, W1, dinv, (unsigned short*)g1b, NN);
    k_gather128<true><<<(NN + 3) / 4, 256, 0, stream>>>(rowptr, csr, g1b, dinv, b1, h1r, NN, EE);

    // layer 2: g2b = bf16((h1r@W2)*dinv) ; out = dinv*(agg+g2) + b2
    k_gemm<64, 4><<<(NN + 63) / 64, 256, 0, stream>>>(h1r, W2, dinv, g2b, NN);
    k_gather64<false><<<(NN + 3) / 4, 256, 0, stream>>>(rowptr, csr, g2b, dinv, b2, out, NN, EE);
}

// Round 6
// 395.782 us; speedup vs baseline: 5.2446x; 1.2521x over previous
//
#include <hip/hip_runtime.h>

static constexpr int NN = 100000;    // nodes
static constexpr int EE = 1600000;   // edges (before self-loops)
static constexpr int BSZ = 64;       // nodes per bucket
static constexpr int NB = (NN + BSZ - 1) / BSZ;   // 1563 buckets
static constexpr int TILE = 4096;    // edges per binning block

// ---- bf16 helpers (storage-only; math stays fp32) ----

__device__ __forceinline__ unsigned short f2bf(float f) {   // round-to-nearest-even
    unsigned u = __float_as_uint(f);
    u += 0x7FFFu + ((u >> 16) & 1u);
    return (unsigned short)(u >> 16);
}
__device__ __forceinline__ float bfl(unsigned u) { return __uint_as_float(u << 16); }
__device__ __forceinline__ float bfh(unsigned u) { return __uint_as_float(u & 0xFFFF0000u); }

// ---------------- bucket histogram (per-tile LDS, then global add) ---------

__global__ __launch_bounds__(256) void k_bhist(const int* __restrict__ dst,
                                               int* __restrict__ bcnt, int E) {
    __shared__ int l[NB];
    const int t = threadIdx.x;
    for (int i = t; i < NB; i += 256) l[i] = 0;
    __syncthreads();
    const int e0 = blockIdx.x * TILE;
#pragma unroll
    for (int k = 0; k < TILE / 256; ++k) {
        int e = e0 + k * 256 + t;
        if (e < E) atomicAdd(&l[dst[e] >> 6], 1);
    }
    __syncthreads();
    for (int i = t; i < NB; i += 256) {
        int c = l[i];
        if (c) atomicAdd(&bcnt[i], c);
    }
}

// ---------------- exclusive scan of bcnt -> bbase[NB+1], init bcur ---------

__global__ __launch_bounds__(256) void k_scanb(const int* __restrict__ bcnt,
                                               int* __restrict__ bbase,
                                               int* __restrict__ bcur, int nb) {
    constexpr int PT = 7;  // 256*7 = 1792 >= NB
    __shared__ int sd[256];
    const int t = threadIdx.x;
    int vals[PT];
    int s = 0;
#pragma unroll
    for (int k = 0; k < PT; ++k) {
        int idx = t * PT + k;
        vals[k] = (idx < nb) ? bcnt[idx] : 0;
        s += vals[k];
    }
    sd[t] = s;
    __syncthreads();
    for (int off = 1; off < 256; off <<= 1) {
        int v = (t >= off) ? sd[t - off] : 0;
        __syncthreads();
        sd[t] += v;
        __syncthreads();
    }
    int run = (t == 0) ? 0 : sd[t - 1];
#pragma unroll
    for (int k = 0; k < PT; ++k) {
        int idx = t * PT + k;
        if (idx < nb) { bbase[idx] = run; bcur[idx] = run; }
        run += vals[k];
    }
    if (t == 255) bbase[nb] = sd[255];   // == EE
}

// ---------------- bin edges into bucket-grouped ebuf (line-combining) ------
// Entry = (src<<6) | local_dst.

__global__ __launch_bounds__(256) void k_bin(const int* __restrict__ src,
                                             const int* __restrict__ dst,
                                             int* __restrict__ bcur,
                                             int* __restrict__ ebuf, int E) {
    constexpr int K = TILE / 256;  // 16 edges per thread
    __shared__ int lcnt[NB];
    __shared__ int lbase[NB];
    const int t = threadIdx.x;
    const int e0 = blockIdx.x * TILE;

    for (int i = t; i < NB; i += 256) lcnt[i] = 0;
    __syncthreads();

    int dreg[K], ofs[K];
#pragma unroll
    for (int k = 0; k < K; ++k) {
        int e = e0 + k * 256 + t;
        if (e < E) {
            int d = dst[e];
            dreg[k] = d;
            ofs[k] = atomicAdd(&lcnt[d >> 6], 1);
        } else dreg[k] = -1;
    }
    __syncthreads();

    for (int i = t; i < NB; i += 256) {
        int c = lcnt[i];
        lbase[i] = c ? atomicAdd(&bcur[i], c) : 0;
    }
    __syncthreads();

#pragma unroll
    for (int k = 0; k < K; ++k) {
        if (dreg[k] >= 0) {
            int e = e0 + k * 256 + t;
            int s = src[e];
            int b = dreg[k] >> 6;
            ebuf[lbase[b] + ofs[k]] = (s << 6) | (dreg[k] & 63);
        }
    }
}

// ---------------- per-bucket: node counts, rowptr, dinv, CSR scatter -------
// One block per bucket.  Counts come from the bucket's ebuf chunk (LDS),
// intra-bucket exclusive scan by wave-0 shuffles, then scatter into csr.

__global__ __launch_bounds__(256) void k_csr(const int* __restrict__ bbase,
                                             const int* __restrict__ ebuf,
                                             int* __restrict__ rowptr,
                                             float* __restrict__ dinv,
                                             int* __restrict__ csr, int n) {
    __shared__ int lcnt[BSZ];
    __shared__ int lofs[BSZ];
    const int b = blockIdx.x, t = threadIdx.x;
    if (t < BSZ) lcnt[t] = 0;
    __syncthreads();
    const int beg = bbase[b], end = bbase[b + 1];
    for (int j = beg + t; j < end; j += 256) atomicAdd(&lcnt[ebuf[j] & 63], 1);
    __syncthreads();
    if (t < BSZ) {                       // wave 0 only (threads 0..63)
        int c = lcnt[t];
        int x = c;
#pragma unroll
        for (int off = 1; off < 64; off <<= 1) {
            int y = __shfl_up(x, off, 64);
            if (t >= off) x += y;
        }
        int exc = x - c;                 // exclusive prefix within bucket
        int node = b * BSZ + t;
        if (node < n) {
            rowptr[node] = beg + exc;
            dinv[node] = rsqrtf((float)c + 1.0f);   // +1 self-loop
        }
        lofs[t] = beg + exc;
    }
    __syncthreads();
    for (int j = beg + t; j < end; j += 256) {
        int e = ebuf[j];
        int pos = atomicAdd(&lofs[e & 63], 1);
        csr[pos] = e >> 6;
    }
}

// ---------------- fp32 GEMM, bf16 out: G = bf16((X @ W) * dinv[row]) -------
// Layer 1: X fp32 [M,128], W [128,128].

__global__ __launch_bounds__(256) void k_gemm128(const float* __restrict__ X,
                                                 const float* __restrict__ W,
                                                 const float* __restrict__ dinv,
                                                 unsigned* __restrict__ G, int M) {
    constexpr int NC = 128, RPT = 8, CT = 32, TM = 64;
    __shared__ float xs[TM * 128];
    const int t = threadIdx.x;
    const int row0 = blockIdx.x * TM;

    for (int idx = t; idx < TM * 32; idx += 256) {
        int r = idx >> 5, c = idx & 31;
        float4 v = make_float4(0.f, 0.f, 0.f, 0.f);
        if (row0 + r < M) v = ((const float4*)(X + (size_t)(row0 + r) * 128))[c];
        ((float4*)xs)[idx] = v;
    }
    __syncthreads();

    const int tc = t % CT;
    const int tr = t / CT;
    float acc[RPT][4];
#pragma unroll
    for (int i = 0; i < RPT; ++i) { acc[i][0]=0.f; acc[i][1]=0.f; acc[i][2]=0.f; acc[i][3]=0.f; }
    const float4* __restrict__ Wv = (const float4*)W;
#pragma unroll 4
    for (int k = 0; k < 128; k += 4) {
        float4 w0 = Wv[(k + 0) * CT + tc];
        float4 w1 = Wv[(k + 1) * CT + tc];
        float4 w2 = Wv[(k + 2) * CT + tc];
        float4 w3 = Wv[(k + 3) * CT + tc];
#pragma unroll
        for (int rr = 0; rr < RPT; ++rr) {
            const float4 xv = *((const float4*)(xs + (tr * RPT + rr) * 128 + k));
            acc[rr][0] = fmaf(xv.x, w0.x, fmaf(xv.y, w1.x, fmaf(xv.z, w2.x, fmaf(xv.w, w3.x, acc[rr][0]))));
            acc[rr][1] = fmaf(xv.x, w0.y, fmaf(xv.y, w1.y, fmaf(xv.z, w2.y, fmaf(xv.w, w3.y, acc[rr][1]))));
            acc[rr][2] = fmaf(xv.x, w0.z, fmaf(xv.y, w1.z, fmaf(xv.z, w2.z, fmaf(xv.w, w3.z, acc[rr][2]))));
            acc[rr][3] = fmaf(xv.x, w0.w, fmaf(xv.y, w1.w, fmaf(xv.z, w2.w, fmaf(xv.w, w3.w, acc[rr][3]))));
        }
    }
#pragma unroll
    for (int rr = 0; rr < RPT; ++rr) {
        int r = row0 + tr * RPT + rr;
        if (r < M) {
            float s = dinv[r];
            uint2 p;
            p.x = (unsigned)f2bf(acc[rr][0] * s) | ((unsigned)f2bf(acc[rr][1] * s) << 16);
            p.y = (unsigned)f2bf(acc[rr][2] * s) | ((unsigned)f2bf(acc[rr][3] * s) << 16);
            ((uint2*)G)[(size_t)r * 32 + tc] = p;   // row stride 64 uints
        }
    }
}

// Layer 2: X bf16 [M,128] (unpacked to fp32 in LDS), W [128,64].

__global__ __launch_bounds__(256) void k_gemm64(const unsigned* __restrict__ X,
                                                const float* __restrict__ W,
                                                const float* __restrict__ dinv,
                                                unsigned* __restrict__ G, int M) {
    constexpr int NC = 64, RPT = 4, CT = 16, TM = 64;
    __shared__ float xs[TM * 128];
    const int t = threadIdx.x;
    const int row0 = blockIdx.x * TM;

    for (int idx = t; idx < TM * 32; idx += 256) {
        int r = idx >> 5, c = idx & 31;
        uint2 u = make_uint2(0u, 0u);
        if (row0 + r < M) u = ((const uint2*)(X + (size_t)(row0 + r) * 64))[c];
        ((float4*)xs)[idx] = make_float4(bfl(u.x), bfh(u.x), bfl(u.y), bfh(u.y));
    }
    __syncthreads();

    const int tc = t % CT;
    const int tr = t / CT;
    float acc[RPT][4];
#pragma unroll
    for (int i = 0; i < RPT; ++i) { acc[i][0]=0.f; acc[i][1]=0.f; acc[i][2]=0.f; acc[i][3]=0.f; }
    const float4* __restrict__ Wv = (const float4*)W;
#pragma unroll 4
    for (int k = 0; k < 128; k += 4) {
        float4 w0 = Wv[(k + 0) * CT + tc];
        float4 w1 = Wv[(k + 1) * CT + tc];
        float4 w2 = Wv[(k + 2) * CT + tc];
        float4 w3 = Wv[(k + 3) * CT + tc];
#pragma unroll
        for (int rr = 0; rr < RPT; ++rr) {
            const float4 xv = *((const float4*)(xs + (tr * RPT + rr) * 128 + k));
            acc[rr][0] = fmaf(xv.x, w0.x, fmaf(xv.y, w1.x, fmaf(xv.z, w2.x, fmaf(xv.w, w3.x, acc[rr][0]))));
            acc[rr][1] = fmaf(xv.x, w0.y, fmaf(xv.y, w1.y, fmaf(xv.z, w2.y, fmaf(xv.w, w3.y, acc[rr][1]))));
            acc[rr][2] = fmaf(xv.x, w0.z, fmaf(xv.y, w1.z, fmaf(xv.z, w2.z, fmaf(xv.w, w3.z, acc[rr][2]))));
            acc[rr][3] = fmaf(xv.x, w0.w, fmaf(xv.y, w1.w, fmaf(xv.z, w2.w, fmaf(xv.w, w3.w, acc[rr][3]))));
        }
    }
#pragma unroll
    for (int rr = 0; rr < RPT; ++rr) {
        int r = row0 + tr * RPT + rr;
        if (r < M) {
            float s = dinv[r];
            uint2 p;
            p.x = (unsigned)f2bf(acc[rr][0] * s) | ((unsigned)f2bf(acc[rr][1] * s) << 16);
            p.y = (unsigned)f2bf(acc[rr][2] * s) | ((unsigned)f2bf(acc[rr][3] * s) << 16);
            ((uint2*)G)[(size_t)r * 16 + tc] = p;   // row stride 32 uints
        }
    }
}

// ---------------- gather + fused epilogue, dual-row loads ------------------
// Persistent waves; wave per node (grid-stride).  Lanes 0-31 fetch edge e0's
// row, lanes 32-63 edge e1's (uint2/lane) -> 16 edges in flight per group.
// Cross-half shfl_xor(32) reduction, then half-wave epilogue + store.
// Layer 1: out = bf16(relu(dinv*(agg+g) + bias))

__global__ __launch_bounds__(256) void k_gather128(const int* __restrict__ rowptr,
                                                   const int* __restrict__ csr,
                                                   const unsigned* __restrict__ G,
                                                   const float* __restrict__ dinv,
                                                   const float* __restrict__ bias,
                                                   unsigned* __restrict__ OUT,
                                                   int n, int E, int nwaves) {
    const int wid = blockIdx.x * 4 + (threadIdx.x >> 6);
    const int lane = threadIdx.x & 63;
    const int sub = lane & 31;
    const int half = lane >> 5;
    for (int node = wid; node < n; node += nwaves) {
        const int beg = rowptr[node];
        const int end = (node == n - 1) ? E : rowptr[node + 1];
        float a0 = 0.f, a1 = 0.f, a2 = 0.f, a3 = 0.f;
        for (int c = beg; c < end; c += 64) {
            int ec = end - c; if (ec > 64) ec = 64;
            const int idx = csr[c + ((lane < ec) ? lane : 0)];
            int pb = 0;
            for (; pb + 16 <= ec; pb += 16) {          // full groups: no predication
#pragma unroll
                for (int q = 0; q < 8; ++q) {
                    int s = __shfl(idx, pb + 2 * q + half, 64);
                    uint2 v = *((const uint2*)(G + (size_t)s * 64 + 2 * sub));
                    a0 += bfl(v.x); a1 += bfh(v.x); a2 += bfl(v.y); a3 += bfh(v.y);
                }
            }
            if (pb < ec) {                             // predicated tail group
#pragma unroll
                for (int q = 0; q < 8; ++q) {
                    int e = pb + 2 * q + half;
                    bool valid = e < ec;
                    int s = __shfl(idx, valid ? e : 0, 64);
                    uint2 v = *((const uint2*)(G + (size_t)s * 64 + 2 * sub));
                    if (valid) { a0 += bfl(v.x); a1 += bfh(v.x); a2 += bfl(v.y); a3 += bfh(v.y); }
                }
            }
        }
        a0 += __shfl_xor(a0, 32, 64);
        a1 += __shfl_xor(a1, 32, 64);
        a2 += __shfl_xor(a2, 32, 64);
        a3 += __shfl_xor(a3, 32, 64);
        if (half == 0) {
            uint2 vs = *((const uint2*)(G + (size_t)node * 64 + 2 * sub));  // self-loop
            a0 += bfl(vs.x); a1 += bfh(vs.x); a2 += bfl(vs.y); a3 += bfh(vs.y);
            const float di = dinv[node];
            const float4 bv = ((const float4*)bias)[sub];
            float r0 = fmaf(a0, di, bv.x), r1 = fmaf(a1, di, bv.y);
            float r2 = fmaf(a2, di, bv.z), r3 = fmaf(a3, di, bv.w);
            r0 = fmaxf(r0, 0.f); r1 = fmaxf(r1, 0.f);
            r2 = fmaxf(r2, 0.f); r3 = fmaxf(r3, 0.f);
            uint2 p;
            p.x = (unsigned)f2bf(r0) | ((unsigned)f2bf(r1) << 16);
            p.y = (unsigned)f2bf(r2) | ((unsigned)f2bf(r3) << 16);
            ((uint2*)OUT)[(size_t)node * 32 + sub] = p;
        }
    }
}

// Layer 2: out = fp32(dinv*(agg+g) + bias), row = 32 uints (64 bf16)

__global__ __launch_bounds__(256) void k_gather64(const int* __restrict__ rowptr,
                                                  const int* __restrict__ csr,
                                                  const unsigned* __restrict__ G,
                                                  const float* __restrict__ dinv,
                                                  const float* __restrict__ bias,
                                                  float* __restrict__ OUT,
                                                  int n, int E, int nwaves) {
    const int wid = blockIdx.x * 4 + (threadIdx.x >> 6);
    const int lane = threadIdx.x & 63;
    const int sub = lane & 31;
    const int half = lane >> 5;
    for (int node = wid; node < n; node += nwaves) {
        const int beg = rowptr[node];
        const int end = (node == n - 1) ? E : rowptr[node + 1];
        float a0 = 0.f, a1 = 0.f;
        for (int c = beg; c < end; c += 64) {
            int ec = end - c; if (ec > 64) ec = 64;
            const int idx = csr[c + ((lane < ec) ? lane : 0)];
            int pb = 0;
            for (; pb + 16 <= ec; pb += 16) {
#pragma unroll
                for (int q = 0; q < 8; ++q) {
                    int s = __shfl(idx, pb + 2 * q + half, 64);
                    unsigned v = G[(size_t)s * 32 + sub];
                    a0 += bfl(v); a1 += bfh(v);
                }
            }
            if (pb < ec) {
#pragma unroll
                for (int q = 0; q < 8; ++q) {
                    int e = pb + 2 * q + half;
                    bool valid = e < ec;
                    int s = __shfl(idx, valid ? e : 0, 64);
                    unsigned v = G[(size_t)s * 32 + sub];
                    if (valid) { a0 += bfl(v); a1 += bfh(v); }
                }
            }
        }
        a0 += __shfl_xor(a0, 32, 64);
        a1 += __shfl_xor(a1, 32, 64);
        if (half == 0) {
            unsigned vs = G[(size_t)node * 32 + sub];    // self-loop
            a0 += bfl(vs); a1 += bfh(vs);
            const float di = dinv[node];
            const float2 bv = ((const float2*)bias)[sub];
            float2 r;
            r.x = fmaf(a0, di, bv.x);
            r.y = fmaf(a1, di, bv.y);
            ((float2*)OUT)[(size_t)node * 32 + sub] = r;
        }
    }
}

// ---------------- launch ----------------

extern "C" void kernel_launch(void* const* d_in, const int* in_sizes, int n_in,
                              void* d_out, int out_size, void* d_ws, size_t ws_size,
                              hipStream_t stream) {
    const float* x  = (const float*)d_in[0];
    const float* W1 = (const float*)d_in[1];
    const float* b1 = (const float*)d_in[2];
    const float* W2 = (const float*)d_in[3];
    const float* b2 = (const float*)d_in[4];
    const int*   ei = (const int*)d_in[5];   // [2, E] int32
    const int* src = ei;
    const int* dst = ei + EE;
    float* out = (float*)d_out;

    // ws (4-byte words):
    // bcnt NB | bbase NB+1 | bcur NB | dinv N | rowptr N | ebuf E | csr E
    // g1b N*64 u | h1b N*64 u | g2b N*32 u
    int*   bcnt   = (int*)d_ws;                   // NB
    int*   bbase  = bcnt + NB;                    // NB+1
    int*   bcur   = bbase + NB + 1;               // NB
    float* dinv   = (float*)(bcur + NB);          // N
    int*   rowptr = (int*)(dinv + NN);            // N
    int*   ebuf   = rowptr + NN;                  // E
    int*   csr    = ebuf + EE;                    // E
    unsigned* g1b = (unsigned*)(csr + EE);        // N*64
    unsigned* h1b = g1b + (size_t)NN * 64;        // N*64
    unsigned* g2b = h1b + (size_t)NN * 64;        // N*32

    constexpr int GB = 2048;          // gather blocks (8 blocks/CU, persistent)
    constexpr int NW = GB * 4;        // gather waves

    hipMemsetAsync(bcnt, 0, NB * sizeof(int), stream);
    k_bhist<<<(EE + TILE - 1) / TILE, 256, 0, stream>>>(dst, bcnt, EE);
    k_scanb<<<1, 256, 0, stream>>>(bcnt, bbase, bcur, NB);
    k_bin<<<(EE + TILE - 1) / TILE, 256, 0, stream>>>(src, dst, bcur, ebuf, EE);
    k_csr<<<NB, 256, 0, stream>>>(bbase, ebuf, rowptr, dinv, csr, NN);

    // layer 1: g1b = bf16((x@W1)*dinv) ; h1b = bf16(relu(dinv*(agg+g1)+b1))
    k_gemm128<<<(NN + 63) / 64, 256, 0, stream>>>(x, W1, dinv, g1b, NN);
    k_gather128<<<GB, 256, 0, stream>>>(rowptr, csr, g1b, dinv, b1, h1b, NN, EE, NW);

    // layer 2: g2b = bf16((h1b@W2)*dinv) ; out = dinv*(agg+g2)+b2  [fp32]
    k_gemm64<<<(NN + 63) / 64, 256, 0, stream>>>(h1b, W2, dinv, g2b, NN);
    k_gather64<<<GB, 256, 0, stream>>>(rowptr, csr, g2b, dinv, b2, out, NN, EE, NW);
}

// Round 8
// 372.673 us; speedup vs baseline: 5.5698x; 1.0620x over previous
//
#include <hip/hip_runtime.h>

static constexpr int NN = 100000;    // nodes
static constexpr int EE = 1600000;   // edges (before self-loops)
static constexpr int BSZ = 64;       // nodes per bucket
static constexpr int NB = (NN + BSZ - 1) / BSZ;   // 1563 buckets
static constexpr int TILE = 4096;    // edges per binning block

// ---- bf16 helpers (storage-only; math stays fp32) ----

__device__ __forceinline__ unsigned short f2bf(float f) {   // round-to-nearest-even
    unsigned u = __float_as_uint(f);
    u += 0x7FFFu + ((u >> 16) & 1u);
    return (unsigned short)(u >> 16);
}
__device__ __forceinline__ float bfl(unsigned u) { return __uint_as_float(u << 16); }
__device__ __forceinline__ float bfh(unsigned u) { return __uint_as_float(u & 0xFFFF0000u); }

typedef __attribute__((ext_vector_type(8))) short short8;    // 8 bf16 (4 VGPRs)
typedef __attribute__((ext_vector_type(4))) float float4v;   // MFMA acc

// ---------------- bucket histogram (per-tile LDS, then global add) ---------

__global__ __launch_bounds__(256) void k_bhist(const int* __restrict__ dst,
                                               int* __restrict__ bcnt, int E) {
    __shared__ int l[NB];
    const int t = threadIdx.x;
    for (int i = t; i < NB; i += 256) l[i] = 0;
    __syncthreads();
    const int e0 = blockIdx.x * TILE;
#pragma unroll
    for (int k = 0; k < TILE / 256; ++k) {
        int e = e0 + k * 256 + t;
        if (e < E) atomicAdd(&l[dst[e] >> 6], 1);
    }
    __syncthreads();
    for (int i = t; i < NB; i += 256) {
        int c = l[i];
        if (c) atomicAdd(&bcnt[i], c);
    }
}

// ---------------- exclusive scan of bcnt -> bbase[NB+1], init bcur ---------

__global__ __launch_bounds__(256) void k_scanb(const int* __restrict__ bcnt,
                                               int* __restrict__ bbase,
                                               int* __restrict__ bcur, int nb) {
    constexpr int PT = 7;  // 256*7 = 1792 >= NB
    __shared__ int sd[256];
    const int t = threadIdx.x;
    int vals[PT];
    int s = 0;
#pragma unroll
    for (int k = 0; k < PT; ++k) {
        int idx = t * PT + k;
        vals[k] = (idx < nb) ? bcnt[idx] : 0;
        s += vals[k];
    }
    sd[t] = s;
    __syncthreads();
    for (int off = 1; off < 256; off <<= 1) {
        int v = (t >= off) ? sd[t - off] : 0;
        __syncthreads();
        sd[t] += v;
        __syncthreads();
    }
    int run = (t == 0) ? 0 : sd[t - 1];
#pragma unroll
    for (int k = 0; k < PT; ++k) {
        int idx = t * PT + k;
        if (idx < nb) { bbase[idx] = run; bcur[idx] = run; }
        run += vals[k];
    }
    if (t == 255) bbase[nb] = sd[255];   // == EE
}

// ---------------- bin edges into bucket-grouped ebuf (line-combining) ------
// Entry = (src<<6) | local_dst.

__global__ __launch_bounds__(256) void k_bin(const int* __restrict__ src,
                                             const int* __restrict__ dst,
                                             int* __restrict__ bcur,
                                             int* __restrict__ ebuf, int E) {
    constexpr int K = TILE / 256;  // 16 edges per thread
    __shared__ int lcnt[NB];
    __shared__ int lbase[NB];
    const int t = threadIdx.x;
    const int e0 = blockIdx.x * TILE;

    for (int i = t; i < NB; i += 256) lcnt[i] = 0;
    __syncthreads();

    int dreg[K], ofs[K];
#pragma unroll
    for (int k = 0; k < K; ++k) {
        int e = e0 + k * 256 + t;
        if (e < E) {
            int d = dst[e];
            dreg[k] = d;
            ofs[k] = atomicAdd(&lcnt[d >> 6], 1);
        } else dreg[k] = -1;
    }
    __syncthreads();

    for (int i = t; i < NB; i += 256) {
        int c = lcnt[i];
        lbase[i] = c ? atomicAdd(&bcur[i], c) : 0;
    }
    __syncthreads();

#pragma unroll
    for (int k = 0; k < K; ++k) {
        if (dreg[k] >= 0) {
            int e = e0 + k * 256 + t;
            int s = src[e];
            int b = dreg[k] >> 6;
            ebuf[lbase[b] + ofs[k]] = (s << 6) | (dreg[k] & 63);
        }
    }
}

// ---------------- per-bucket: node counts, rowptr, dinv, CSR scatter -------

__global__ __launch_bounds__(256) void k_csr(const int* __restrict__ bbase,
                                             const int* __restrict__ ebuf,
                                             int* __restrict__ rowptr,
                                             float* __restrict__ dinv,
                                             int* __restrict__ csr, int n) {
    __shared__ int lcnt[BSZ];
    __shared__ int lofs[BSZ];
    const int b = blockIdx.x, t = threadIdx.x;
    if (t < BSZ) lcnt[t] = 0;
    __syncthreads();
    const int beg = bbase[b], end = bbase[b + 1];
    for (int j = beg + t; j < end; j += 256) atomicAdd(&lcnt[ebuf[j] & 63], 1);
    __syncthreads();
    if (t < BSZ) {                       // wave 0 only (threads 0..63)
        int c = lcnt[t];
        int x = c;
#pragma unroll
        for (int off = 1; off < 64; off <<= 1) {
            int y = __shfl_up(x, off, 64);
            if (t >= off) x += y;
        }
        int exc = x - c;                 // exclusive prefix within bucket
        int node = b * BSZ + t;
        if (node < n) {
            rowptr[node] = beg + exc;
            dinv[node] = rsqrtf((float)c + 1.0f);   // +1 self-loop
        }
        lofs[t] = beg + exc;
    }
    __syncthreads();
    for (int j = beg + t; j < end; j += 256) {
        int e = ebuf[j];
        int pos = atomicAdd(&lofs[e & 63], 1);
        csr[pos] = e >> 6;
    }
}

// ---------------- one-time weight prep: W^T in bf16 ------------------------
// W1 [128,128] -> W1t[n][k] bf16 ; W2 [128,64] -> W2t[n][k] bf16

__global__ __launch_bounds__(256) void k_wprep(const float* __restrict__ W1,
                                               const float* __restrict__ W2,
                                               unsigned short* __restrict__ W1t,
                                               unsigned short* __restrict__ W2t) {
    int idx = blockIdx.x * 256 + threadIdx.x;
    if (idx < 16384) {
        int n = idx >> 7, k = idx & 127;
        W1t[idx] = f2bf(W1[k * 128 + n]);
    } else if (idx < 16384 + 8192) {
        int j = idx - 16384;
        int n = j >> 7, k = j & 127;
        W2t[j] = f2bf(W2[k * 64 + n]);
    }
}

// ---------------- MFMA GEMM layer 1: G = bf16((X @ W1) * dinv[row]) --------
// X fp32 [M,128] -> bf16 A-frags in-register; W1t bf16 [n][k] via L1.
// 4 waves/block x 16 rows; per-wave LDS staging only for coalesced pack-out.
// Layouts (learn_hip verified): A[m=lane&15][k=quad*8+j], B[n=lane&15][k=quad*8+j],
// C/D col=lane&15, row=quad*4+reg.

__global__ __launch_bounds__(256) void k_gemm128m(const float* __restrict__ X,
                                                  const unsigned short* __restrict__ W1t,
                                                  const float* __restrict__ dinv,
                                                  unsigned* __restrict__ G, int M) {
    __shared__ float cls[4 * 16 * 132];    // per-wave [16][132] (pad: 2-way max)
    const int t = threadIdx.x;
    const int w = t >> 6, lane = t & 63;
    const int quad = lane >> 4, m16 = lane & 15;
    const int row0 = blockIdx.x * 64 + w * 16;
    int arow = row0 + m16; if (arow >= M) arow = M - 1;

    short8 afrag[4];
#pragma unroll
    for (int ks = 0; ks < 4; ++ks) {
        const float* p = X + (size_t)arow * 128 + ks * 32 + quad * 8;
        float4 u0 = ((const float4*)p)[0];
        float4 u1 = ((const float4*)p)[1];
        short8 a;
        a[0] = (short)f2bf(u0.x); a[1] = (short)f2bf(u0.y);
        a[2] = (short)f2bf(u0.z); a[3] = (short)f2bf(u0.w);
        a[4] = (short)f2bf(u1.x); a[5] = (short)f2bf(u1.y);
        a[6] = (short)f2bf(u1.z); a[7] = (short)f2bf(u1.w);
        afrag[ks] = a;
    }
    float* myc = cls + w * 16 * 132;
#pragma unroll
    for (int nt = 0; nt < 8; ++nt) {
        float4v acc = {0.f, 0.f, 0.f, 0.f};
#pragma unroll
        for (int ks = 0; ks < 4; ++ks) {
            const short8 b = *((const short8*)(W1t + (size_t)(nt * 16 + m16) * 128 + ks * 32 + quad * 8));
            acc = __builtin_amdgcn_mfma_f32_16x16x32_bf16(afrag[ks], b, acc, 0, 0, 0);
        }
#pragma unroll
        for (int r = 0; r < 4; ++r)
            myc[(quad * 4 + r) * 132 + nt * 16 + m16] = acc[r];
    }
    __syncthreads();   // intra-wave only logically, but cheap; ensures LDS vis
    // pack + coalesced store: 16 rows x 32 uint2 chunks = 512 items, 8/lane
#pragma unroll
    for (int i = 0; i < 8; ++i) {
        int idx = i * 64 + lane;
        int r = idx >> 5, c = idx & 31;
        int grow = row0 + r;
        if (grow < M) {
            float4 v = *((const float4*)(myc + r * 132 + c * 4));
            float s = dinv[grow];
            uint2 p;
            p.x = (unsigned)f2bf(v.x * s) | ((unsigned)f2bf(v.y * s) << 16);
            p.y = (unsigned)f2bf(v.z * s) | ((unsigned)f2bf(v.w * s) << 16);
            ((uint2*)G)[(size_t)grow * 32 + c] = p;
        }
    }
}

// ---------------- MFMA GEMM layer 2: G = bf16((Xbf16 @ W2) * dinv[row]) ----

__global__ __launch_bounds__(256) void k_gemm64m(const unsigned short* __restrict__ X,
                                                 const unsigned short* __restrict__ W2t,
                                                 const float* __restrict__ dinv,
                                                 unsigned* __restrict__ G, int M) {
    __shared__ float cls[4 * 16 * 68];     // per-wave [16][68]
    const int t = threadIdx.x;
    const int w = t >> 6, lane = t & 63;
    const int quad = lane >> 4, m16 = lane & 15;
    const int row0 = blockIdx.x * 64 + w * 16;
    int arow = row0 + m16; if (arow >= M) arow = M - 1;

    short8 afrag[4];
#pragma unroll
    for (int ks = 0; ks < 4; ++ks)
        afrag[ks] = *((const short8*)(X + (size_t)arow * 128 + ks * 32 + quad * 8));

    float* myc = cls + w * 16 * 68;
#pragma unroll
    for (int nt = 0; nt < 4; ++nt) {
        float4v acc = {0.f, 0.f, 0.f, 0.f};
#pragma unroll
        for (int ks = 0; ks < 4; ++ks) {
            const short8 b = *((const short8*)(W2t + (size_t)(nt * 16 + m16) * 128 + ks * 32 + quad * 8));
            acc = __builtin_amdgcn_mfma_f32_16x16x32_bf16(afrag[ks], b, acc, 0, 0, 0);
        }
#pragma unroll
        for (int r = 0; r < 4; ++r)
            myc[(quad * 4 + r) * 68 + nt * 16 + m16] = acc[r];
    }
    __syncthreads();
    // pack + store: 16 rows x 16 uint2 chunks = 256 items, 4/lane
#pragma unroll
    for (int i = 0; i < 4; ++i) {
        int idx = i * 64 + lane;
        int r = idx >> 4, c = idx & 15;
        int grow = row0 + r;
        if (grow < M) {
            float4 v = *((const float4*)(myc + r * 68 + c * 4));
            float s = dinv[grow];
            uint2 p;
            p.x = (unsigned)f2bf(v.x * s) | ((unsigned)f2bf(v.y * s) << 16);
            p.y = (unsigned)f2bf(v.z * s) | ((unsigned)f2bf(v.w * s) << 16);
            ((uint2*)G)[(size_t)grow * 16 + c] = p;
        }
    }
}

// ---------------- gather + fused epilogue, dual-row loads ------------------
// Persistent waves; wave per node (grid-stride).  Lanes 0-31 fetch edge e0's
// row, lanes 32-63 edge e1's (uint2/lane).  Cross-half shfl_xor(32) reduce.
// Layer 1: out = bf16(relu(dinv*(agg+g) + bias))

__global__ __launch_bounds__(256) void k_gather128(const int* __restrict__ rowptr,
                                                   const int* __restrict__ csr,
                                                   const unsigned* __restrict__ G,
                                                   const float* __restrict__ dinv,
                                                   const float* __restrict__ bias,
                                                   unsigned* __restrict__ OUT,
                                                   int n, int E, int nwaves) {
    const int wid = blockIdx.x * 4 + (threadIdx.x >> 6);
    const int lane = threadIdx.x & 63;
    const int sub = lane & 31;
    const int half = lane >> 5;
    for (int node = wid; node < n; node += nwaves) {
        const int beg = rowptr[node];
        const int end = (node == n - 1) ? E : rowptr[node + 1];
        float a0 = 0.f, a1 = 0.f, a2 = 0.f, a3 = 0.f;
        for (int c = beg; c < end; c += 64) {
            int ec = end - c; if (ec > 64) ec = 64;
            const int idx = csr[c + ((lane < ec) ? lane : 0)];
            int pb = 0;
            for (; pb + 16 <= ec; pb += 16) {          // full groups: no predication
#pragma unroll
                for (int q = 0; q < 8; ++q) {
                    int s = __shfl(idx, pb + 2 * q + half, 64);
                    uint2 v = *((const uint2*)(G + (size_t)s * 64 + 2 * sub));
                    a0 += bfl(v.x); a1 += bfh(v.x); a2 += bfl(v.y); a3 += bfh(v.y);
                }
            }
            if (pb < ec) {                             // predicated tail group
#pragma unroll
                for (int q = 0; q < 8; ++q) {
                    int e = pb + 2 * q + half;
                    bool valid = e < ec;
                    int s = __shfl(idx, valid ? e : 0, 64);
                    uint2 v = *((const uint2*)(G + (size_t)s * 64 + 2 * sub));
                    if (valid) { a0 += bfl(v.x); a1 += bfh(v.x); a2 += bfl(v.y); a3 += bfh(v.y); }
                }
            }
        }
        a0 += __shfl_xor(a0, 32, 64);
        a1 += __shfl_xor(a1, 32, 64);
        a2 += __shfl_xor(a2, 32, 64);
        a3 += __shfl_xor(a3, 32, 64);
        if (half == 0) {
            uint2 vs = *((const uint2*)(G + (size_t)node * 64 + 2 * sub));  // self-loop
            a0 += bfl(vs.x); a1 += bfh(vs.x); a2 += bfl(vs.y); a3 += bfh(vs.y);
            const float di = dinv[node];
            const float4 bv = ((const float4*)bias)[sub];
            float r0 = fmaf(a0, di, bv.x), r1 = fmaf(a1, di, bv.y);
            float r2 = fmaf(a2, di, bv.z), r3 = fmaf(a3, di, bv.w);
            r0 = fmaxf(r0, 0.f); r1 = fmaxf(r1, 0.f);
            r2 = fmaxf(r2, 0.f); r3 = fmaxf(r3, 0.f);
            uint2 p;
            p.x = (unsigned)f2bf(r0) | ((unsigned)f2bf(r1) << 16);
            p.y = (unsigned)f2bf(r2) | ((unsigned)f2bf(r3) << 16);
            ((uint2*)OUT)[(size_t)node * 32 + sub] = p;
        }
    }
}

// Layer 2: out = fp32(dinv*(agg+g) + bias), row = 32 uints (64 bf16)

__global__ __launch_bounds__(256) void k_gather64(const int* __restrict__ rowptr,
                                                  const int* __restrict__ csr,
                                                  const unsigned* __restrict__ G,
                                                  const float* __restrict__ dinv,
                                                  const float* __restrict__ bias,
                                                  float* __restrict__ OUT,
                                                  int n, int E, int nwaves) {
    const int wid = blockIdx.x * 4 + (threadIdx.x >> 6);
    const int lane = threadIdx.x & 63;
    const int sub = lane & 31;
    const int half = lane >> 5;
    for (int node = wid; node < n; node += nwaves) {
        const int beg = rowptr[node];
        const int end = (node == n - 1) ? E : rowptr[node + 1];
        float a0 = 0.f, a1 = 0.f;
        for (int c = beg; c < end; c += 64) {
            int ec = end - c; if (ec > 64) ec = 64;
            const int idx = csr[c + ((lane < ec) ? lane : 0)];
            int pb = 0;
            for (; pb + 16 <= ec; pb += 16) {
#pragma unroll
                for (int q = 0; q < 8; ++q) {
                    int s = __shfl(idx, pb + 2 * q + half, 64);
                    unsigned v = G[(size_t)s * 32 + sub];
                    a0 += bfl(v); a1 += bfh(v);
                }
            }
            if (pb < ec) {
#pragma unroll
                for (int q = 0; q < 8; ++q) {
                    int e = pb + 2 * q + half;
                    bool valid = e < ec;
                    int s = __shfl(idx, valid ? e : 0, 64);
                    unsigned v = G[(size_t)s * 32 + sub];
                    if (valid) { a0 += bfl(v); a1 += bfh(v); }
                }
            }
        }
        a0 += __shfl_xor(a0, 32, 64);
        a1 += __shfl_xor(a1, 32, 64);
        if (half == 0) {
            unsigned vs = G[(size_t)node * 32 + sub];    // self-loop
            a0 += bfl(vs); a1 += bfh(vs);
            const float di = dinv[node];
            const float2 bv = ((const float2*)bias)[sub];
            float2 r;
            r.x = fmaf(a0, di, bv.x);
            r.y = fmaf(a1, di, bv.y);
            ((float2*)OUT)[(size_t)node * 32 + sub] = r;
        }
    }
}

// ---------------- launch ----------------

extern "C" void kernel_launch(void* const* d_in, const int* in_sizes, int n_in,
                              void* d_out, int out_size, void* d_ws, size_t ws_size,
                              hipStream_t stream) {
    const float* x  = (const float*)d_in[0];
    const float* W1 = (const float*)d_in[1];
    const float* b1 = (const float*)d_in[2];
    const float* W2 = (const float*)d_in[3];
    const float* b2 = (const float*)d_in[4];
    const int*   ei = (const int*)d_in[5];   // [2, E] int32
    const int* src = ei;
    const int* dst = ei + EE;
    float* out = (float*)d_out;

    // ws (4-byte words):
    // bcnt NB | bbase NB+1 | bcur NB | dinv N | rowptr N | ebuf E | csr E
    // g1b N*64 u | h1b N*64 u | g2b N*32 u | w1t 8192 u | w2t 4096 u
    int*   bcnt   = (int*)d_ws;                   // NB
    int*   bbase  = bcnt + NB;                    // NB+1
    int*   bcur   = bbase + NB + 1;               // NB
    float* dinv   = (float*)(bcur + NB);          // N
    int*   rowptr = (int*)(dinv + NN);            // N
    int*   ebuf   = rowptr + NN;                  // E
    int*   csr    = ebuf + EE;                    // E
    unsigned* g1b = (unsigned*)(csr + EE);        // N*64
    unsigned* h1b = g1b + (size_t)NN * 64;        // N*64
    unsigned* g2b = h1b + (size_t)NN * 64;        // N*32
    unsigned short* w1t = (unsigned short*)(g2b + (size_t)NN * 32);  // 16384 bf16
    unsigned short* w2t = w1t + 16384;                               // 8192 bf16

    constexpr int GB = 2048;          // gather blocks (persistent)
    constexpr int NW = GB * 4;        // gather waves

    (void)hipMemsetAsync(bcnt, 0, NB * sizeof(int), stream);
    k_wprep<<<96, 256, 0, stream>>>(W1, W2, w1t, w2t);
    k_bhist<<<(EE + TILE - 1) / TILE, 256, 0, stream>>>(dst, bcnt, EE);
    k_scanb<<<1, 256, 0, stream>>>(bcnt, bbase, bcur, NB);
    k_bin<<<(EE + TILE - 1) / TILE, 256, 0, stream>>>(src, dst, bcur, ebuf, EE);
    k_csr<<<NB, 256, 0, stream>>>(bbase, ebuf, rowptr, dinv, csr, NN);

    // layer 1: g1b = bf16((x@W1)*dinv) ; h1b = bf16(relu(dinv*(agg+g1)+b1))
    k_gemm128m<<<(NN + 63) / 64, 256, 0, stream>>>(x, w1t, dinv, g1b, NN);
    k_gather128<<<GB, 256, 0, stream>>>(rowptr, csr, g1b, dinv, b1, h1b, NN, EE, NW);

    // layer 2: g2b = bf16((h1b@W2)*dinv) ; out = dinv*(agg+g2)+b2  [fp32]
    k_gemm64m<<<(NN + 63) / 64, 256, 0, stream>>>((const unsigned short*)h1b, w2t, dinv, g2b, NN);
    k_gather64<<<GB, 256, 0, stream>>>(rowptr, csr, g2b, dinv, b2, out, NN, EE, NW);
}

// Round 9
// 347.785 us; speedup vs baseline: 5.9684x; 1.0716x over previous
//
#include <hip/hip_runtime.h>

static constexpr int NN = 100000;    // nodes
static constexpr int EE = 1600000;   // edges (before self-loops)
static constexpr int BSZ = 64;       // nodes per bucket
static constexpr int NB = (NN + BSZ - 1) / BSZ;   // 1563 buckets
static constexpr int BCAP = 2048;    // fixed bucket capacity (mean 1024, 32 sigma)
static constexpr int TILE = 2048;    // edges per binning block

// ---- bf16 helpers (storage-only; math stays fp32) ----

__device__ __forceinline__ unsigned short f2bf(float f) {   // round-to-nearest-even
    unsigned u = __float_as_uint(f);
    u += 0x7FFFu + ((u >> 16) & 1u);
    return (unsigned short)(u >> 16);
}
__device__ __forceinline__ float bfl(unsigned u) { return __uint_as_float(u << 16); }
__device__ __forceinline__ float bfh(unsigned u) { return __uint_as_float(u & 0xFFFF0000u); }

typedef __attribute__((ext_vector_type(8))) short short8;    // 8 bf16 (4 VGPRs)
typedef __attribute__((ext_vector_type(4))) float float4v;   // MFMA acc

// ---------------- init: W^T bf16 prep + bucket cursor bases ----------------

__global__ __launch_bounds__(256) void k_init(const float* __restrict__ W1,
                                              const float* __restrict__ W2,
                                              unsigned short* __restrict__ W1t,
                                              unsigned short* __restrict__ W2t,
                                              int* __restrict__ bcur) {
    int idx = blockIdx.x * 256 + threadIdx.x;
    if (idx < 16384) {
        int n = idx >> 7, k = idx & 127;
        W1t[idx] = f2bf(W1[k * 128 + n]);
    } else if (idx < 24576) {
        int j = idx - 16384;
        int n = j >> 7, k = j & 127;
        W2t[j] = f2bf(W2[k * 64 + n]);
    } else if (idx < 24576 + NB) {
        int b = idx - 24576;
        bcur[b] = b * BCAP;
    }
}

// ---------------- bin edges into fixed-stride bucket chunks ----------------
// Per-tile LDS histogram -> one global atomicAdd per (bucket,tile) chunk ->
// chunk-local writes (line-combining).  Entry = (src<<6) | local_dst.

__global__ __launch_bounds__(256) void k_bin(const int* __restrict__ src,
                                             const int* __restrict__ dst,
                                             int* __restrict__ bcur,
                                             int* __restrict__ ebuf, int E) {
    constexpr int K = TILE / 256;  // 8 edges per thread
    __shared__ int lcnt[NB];
    __shared__ int lbase[NB];
    const int t = threadIdx.x;
    const int e0 = blockIdx.x * TILE;

    for (int i = t; i < NB; i += 256) lcnt[i] = 0;
    __syncthreads();

    int dreg[K], ofs[K];
#pragma unroll
    for (int k = 0; k < K; ++k) {
        int e = e0 + k * 256 + t;
        if (e < E) {
            int d = dst[e];
            dreg[k] = d;
            ofs[k] = atomicAdd(&lcnt[d >> 6], 1);
        } else dreg[k] = -1;
    }
    __syncthreads();

    for (int i = t; i < NB; i += 256) {
        int c = lcnt[i];
        lbase[i] = c ? atomicAdd(&bcur[i], c) : 0;
    }
    __syncthreads();

#pragma unroll
    for (int k = 0; k < K; ++k) {
        if (dreg[k] >= 0) {
            int e = e0 + k * 256 + t;
            int s = src[e];
            int b = dreg[k] >> 6;
            ebuf[lbase[b] + ofs[k]] = (s << 6) | (dreg[k] & 63);
        }
    }
}

// ---------------- per-bucket: counts, rowbeg/rowend, dinv, CSR scatter -----
// One block per bucket; bucket chunk = ebuf[b*BCAP .. bcur[b]).

__global__ __launch_bounds__(256) void k_csr(const int* __restrict__ bcur,
                                             const int* __restrict__ ebuf,
                                             int* __restrict__ rowbeg,
                                             int* __restrict__ rowend,
                                             float* __restrict__ dinv,
                                             int* __restrict__ csr, int n) {
    __shared__ int lcnt[BSZ];
    __shared__ int lofs[BSZ];
    const int b = blockIdx.x, t = threadIdx.x;
    if (t < BSZ) lcnt[t] = 0;
    __syncthreads();
    const int beg = b * BCAP, end = bcur[b];
    for (int j = beg + t; j < end; j += 256) atomicAdd(&lcnt[ebuf[j] & 63], 1);
    __syncthreads();
    if (t < BSZ) {                       // wave 0 only (threads 0..63)
        int c = lcnt[t];
        int x = c;
#pragma unroll
        for (int off = 1; off < 64; off <<= 1) {
            int y = __shfl_up(x, off, 64);
            if (t >= off) x += y;
        }
        int exc = x - c;                 // exclusive prefix within bucket
        int node = b * BSZ + t;
        if (node < n) {
            rowbeg[node] = beg + exc;
            rowend[node] = beg + exc + c;
            dinv[node] = rsqrtf((float)c + 1.0f);   // +1 self-loop
        }
        lofs[t] = beg + exc;
    }
    __syncthreads();
    for (int j = beg + t; j < end; j += 256) {
        int e = ebuf[j];
        int pos = atomicAdd(&lofs[e & 63], 1);
        csr[pos] = e >> 6;
    }
}

// ---------------- MFMA GEMM layer 1: G = bf16((X @ W1) * dinv[row]) --------
// Layouts (learn_hip verified): A[m=lane&15][k=quad*8+j], B[n=lane&15][k=quad*8+j],
// C/D col=lane&15, row=quad*4+reg.

__global__ __launch_bounds__(256) void k_gemm128m(const float* __restrict__ X,
                                                  const unsigned short* __restrict__ W1t,
                                                  const float* __restrict__ dinv,
                                                  unsigned* __restrict__ G, int M) {
    __shared__ float cls[4 * 16 * 132];    // per-wave [16][132] (pad: 2-way max)
    const int t = threadIdx.x;
    const int w = t >> 6, lane = t & 63;
    const int quad = lane >> 4, m16 = lane & 15;
    const int row0 = blockIdx.x * 64 + w * 16;
    int arow = row0 + m16; if (arow >= M) arow = M - 1;

    short8 afrag[4];
#pragma unroll
    for (int ks = 0; ks < 4; ++ks) {
        const float* p = X + (size_t)arow * 128 + ks * 32 + quad * 8;
        float4 u0 = ((const float4*)p)[0];
        float4 u1 = ((const float4*)p)[1];
        short8 a;
        a[0] = (short)f2bf(u0.x); a[1] = (short)f2bf(u0.y);
        a[2] = (short)f2bf(u0.z); a[3] = (short)f2bf(u0.w);
        a[4] = (short)f2bf(u1.x); a[5] = (short)f2bf(u1.y);
        a[6] = (short)f2bf(u1.z); a[7] = (short)f2bf(u1.w);
        afrag[ks] = a;
    }
    float* myc = cls + w * 16 * 132;
#pragma unroll
    for (int nt = 0; nt < 8; ++nt) {
        float4v acc = {0.f, 0.f, 0.f, 0.f};
#pragma unroll
        for (int ks = 0; ks < 4; ++ks) {
            const short8 b = *((const short8*)(W1t + (size_t)(nt * 16 + m16) * 128 + ks * 32 + quad * 8));
            acc = __builtin_amdgcn_mfma_f32_16x16x32_bf16(afrag[ks], b, acc, 0, 0, 0);
        }
#pragma unroll
        for (int r = 0; r < 4; ++r)
            myc[(quad * 4 + r) * 132 + nt * 16 + m16] = acc[r];
    }
    __syncthreads();
    // pack + coalesced store: 16 rows x 32 uint2 chunks = 512 items, 8/lane
#pragma unroll
    for (int i = 0; i < 8; ++i) {
        int idx = i * 64 + lane;
        int r = idx >> 5, c = idx & 31;
        int grow = row0 + r;
        if (grow < M) {
            float4 v = *((const float4*)(myc + r * 132 + c * 4));
            float s = dinv[grow];
            uint2 p;
            p.x = (unsigned)f2bf(v.x * s) | ((unsigned)f2bf(v.y * s) << 16);
            p.y = (unsigned)f2bf(v.z * s) | ((unsigned)f2bf(v.w * s) << 16);
            ((uint2*)G)[(size_t)grow * 32 + c] = p;
        }
    }
}

// ---------------- MFMA GEMM layer 2: G = bf16((Xbf16 @ W2) * dinv[row]) ----

__global__ __launch_bounds__(256) void k_gemm64m(const unsigned short* __restrict__ X,
                                                 const unsigned short* __restrict__ W2t,
                                                 const float* __restrict__ dinv,
                                                 unsigned* __restrict__ G, int M) {
    __shared__ float cls[4 * 16 * 68];     // per-wave [16][68]
    const int t = threadIdx.x;
    const int w = t >> 6, lane = t & 63;
    const int quad = lane >> 4, m16 = lane & 15;
    const int row0 = blockIdx.x * 64 + w * 16;
    int arow = row0 + m16; if (arow >= M) arow = M - 1;

    short8 afrag[4];
#pragma unroll
    for (int ks = 0; ks < 4; ++ks)
        afrag[ks] = *((const short8*)(X + (size_t)arow * 128 + ks * 32 + quad * 8));

    float* myc = cls + w * 16 * 68;
#pragma unroll
    for (int nt = 0; nt < 4; ++nt) {
        float4v acc = {0.f, 0.f, 0.f, 0.f};
#pragma unroll
        for (int ks = 0; ks < 4; ++ks) {
            const short8 b = *((const short8*)(W2t + (size_t)(nt * 16 + m16) * 128 + ks * 32 + quad * 8));
            acc = __builtin_amdgcn_mfma_f32_16x16x32_bf16(afrag[ks], b, acc, 0, 0, 0);
        }
#pragma unroll
        for (int r = 0; r < 4; ++r)
            myc[(quad * 4 + r) * 68 + nt * 16 + m16] = acc[r];
    }
    __syncthreads();
    // pack + store: 16 rows x 16 uint2 chunks = 256 items, 4/lane
#pragma unroll
    for (int i = 0; i < 4; ++i) {
        int idx = i * 64 + lane;
        int r = idx >> 4, c = idx & 15;
        int grow = row0 + r;
        if (grow < M) {
            float4 v = *((const float4*)(myc + r * 68 + c * 4));
            float s = dinv[grow];
            uint2 p;
            p.x = (unsigned)f2bf(v.x * s) | ((unsigned)f2bf(v.y * s) << 16);
            p.y = (unsigned)f2bf(v.z * s) | ((unsigned)f2bf(v.w * s) << 16);
            ((uint2*)G)[(size_t)grow * 16 + c] = p;
        }
    }
}

// ---------------- gather + fused epilogue ----------------------------------
// Persistent waves; wave per node (grid-stride).
// Layer 1 (256 B rows): half-wave per edge, 16 edges / 2 KB in flight.
// out = bf16(relu(dinv*(agg+g) + bias))

__global__ __launch_bounds__(256) void k_gather128(const int* __restrict__ rowbeg,
                                                   const int* __restrict__ rowend,
                                                   const int* __restrict__ csr,
                                                   const unsigned* __restrict__ G,
                                                   const float* __restrict__ dinv,
                                                   const float* __restrict__ bias,
                                                   unsigned* __restrict__ OUT,
                                                   int n, int nwaves) {
    const int wid = blockIdx.x * 4 + (threadIdx.x >> 6);
    const int lane = threadIdx.x & 63;
    const int sub = lane & 31;
    const int half = lane >> 5;
    for (int node = wid; node < n; node += nwaves) {
        const int beg = rowbeg[node];
        const int end = rowend[node];
        float a0 = 0.f, a1 = 0.f, a2 = 0.f, a3 = 0.f;
        for (int c = beg; c < end; c += 64) {
            int ec = end - c; if (ec > 64) ec = 64;
            const int idx = csr[c + ((lane < ec) ? lane : 0)];
            int pb = 0;
            for (; pb + 16 <= ec; pb += 16) {          // full groups: no predication
#pragma unroll
                for (int q = 0; q < 8; ++q) {
                    int s = __shfl(idx, pb + 2 * q + half, 64);
                    uint2 v = *((const uint2*)(G + (size_t)s * 64 + 2 * sub));
                    a0 += bfl(v.x); a1 += bfh(v.x); a2 += bfl(v.y); a3 += bfh(v.y);
                }
            }
            if (pb < ec) {                             // predicated tail group
#pragma unroll
                for (int q = 0; q < 8; ++q) {
                    int e = pb + 2 * q + half;
                    bool valid = e < ec;
                    int s = __shfl(idx, valid ? e : 0, 64);
                    uint2 v = *((const uint2*)(G + (size_t)s * 64 + 2 * sub));
                    if (valid) { a0 += bfl(v.x); a1 += bfh(v.x); a2 += bfl(v.y); a3 += bfh(v.y); }
                }
            }
        }
        a0 += __shfl_xor(a0, 32, 64);
        a1 += __shfl_xor(a1, 32, 64);
        a2 += __shfl_xor(a2, 32, 64);
        a3 += __shfl_xor(a3, 32, 64);
        if (half == 0) {
            uint2 vs = *((const uint2*)(G + (size_t)node * 64 + 2 * sub));  // self-loop
            a0 += bfl(vs.x); a1 += bfh(vs.x); a2 += bfl(vs.y); a3 += bfh(vs.y);
            const float di = dinv[node];
            const float4 bv = ((const float4*)bias)[sub];
            float r0 = fmaf(a0, di, bv.x), r1 = fmaf(a1, di, bv.y);
            float r2 = fmaf(a2, di, bv.z), r3 = fmaf(a3, di, bv.w);
            r0 = fmaxf(r0, 0.f); r1 = fmaxf(r1, 0.f);
            r2 = fmaxf(r2, 0.f); r3 = fmaxf(r3, 0.f);
            uint2 p;
            p.x = (unsigned)f2bf(r0) | ((unsigned)f2bf(r1) << 16);
            p.y = (unsigned)f2bf(r2) | ((unsigned)f2bf(r3) << 16);
            ((uint2*)OUT)[(size_t)node * 32 + sub] = p;
        }
    }
}

// Layer 2 (128 B rows): quarter-wave per edge (16 lanes x uint2), 32 edges /
// 4 KB in flight per wave.  out = fp32(dinv*(agg+g) + bias)

__global__ __launch_bounds__(256) void k_gather64(const int* __restrict__ rowbeg,
                                                  const int* __restrict__ rowend,
                                                  const int* __restrict__ csr,
                                                  const unsigned* __restrict__ G,
                                                  const float* __restrict__ dinv,
                                                  const float* __restrict__ bias,
                                                  float* __restrict__ OUT,
                                                  int n, int nwaves) {
    const int wid = blockIdx.x * 4 + (threadIdx.x >> 6);
    const int lane = threadIdx.x & 63;
    const int sub = lane & 15;
    const int qh = lane >> 4;            // 0..3
    for (int node = wid; node < n; node += nwaves) {
        const int beg = rowbeg[node];
        const int end = rowend[node];
        float a0 = 0.f, a1 = 0.f, a2 = 0.f, a3 = 0.f;
        for (int c = beg; c < end; c += 64) {
            int ec = end - c; if (ec > 64) ec = 64;
            const int idx = csr[c + ((lane < ec) ? lane : 0)];
            int pb = 0;
            for (; pb + 32 <= ec; pb += 32) {          // full groups: no predication
#pragma unroll
                for (int q = 0; q < 8; ++q) {
                    int s = __shfl(idx, pb + 4 * q + qh, 64);
                    uint2 v = ((const uint2*)(G + (size_t)s * 32))[sub];
                    a0 += bfl(v.x); a1 += bfh(v.x); a2 += bfl(v.y); a3 += bfh(v.y);
                }
            }
            if (pb < ec) {                             // predicated tail group
#pragma unroll
                for (int q = 0; q < 8; ++q) {
                    int e = pb + 4 * q + qh;
                    bool valid = e < ec;
                    int s = __shfl(idx, valid ? e : 0, 64);
                    uint2 v = ((const uint2*)(G + (size_t)s * 32))[sub];
                    if (valid) { a0 += bfl(v.x); a1 += bfh(v.x); a2 += bfl(v.y); a3 += bfh(v.y); }
                }
            }
        }
        a0 += __shfl_xor(a0, 16, 64); a0 += __shfl_xor(a0, 32, 64);
        a1 += __shfl_xor(a1, 16, 64); a1 += __shfl_xor(a1, 32, 64);
        a2 += __shfl_xor(a2, 16, 64); a2 += __shfl_xor(a2, 32, 64);
        a3 += __shfl_xor(a3, 16, 64); a3 += __shfl_xor(a3, 32, 64);
        if (qh == 0) {
            uint2 vs = ((const uint2*)(G + (size_t)node * 32))[sub];   // self-loop
            a0 += bfl(vs.x); a1 += bfh(vs.x); a2 += bfl(vs.y); a3 += bfh(vs.y);
            const float di = dinv[node];
            const float4 bv = ((const float4*)bias)[sub];
            float4 r;
            r.x = fmaf(a0, di, bv.x);
            r.y = fmaf(a1, di, bv.y);
            r.z = fmaf(a2, di, bv.z);
            r.w = fmaf(a3, di, bv.w);
            ((float4*)OUT)[(size_t)node * 16 + sub] = r;
        }
    }
}

// ---------------- launch ----------------

extern "C" void kernel_launch(void* const* d_in, const int* in_sizes, int n_in,
                              void* d_out, int out_size, void* d_ws, size_t ws_size,
                              hipStream_t stream) {
    const float* x  = (const float*)d_in[0];
    const float* W1 = (const float*)d_in[1];
    const float* b1 = (const float*)d_in[2];
    const float* W2 = (const float*)d_in[3];
    const float* b2 = (const float*)d_in[4];
    const int*   ei = (const int*)d_in[5];   // [2, E] int32
    const int* src = ei;
    const int* dst = ei + EE;
    float* out = (float*)d_out;

    // ws (4-byte words):
    // bcur NB | dinv N | rowbeg N | rowend N | ebuf NB*BCAP | csr NB*BCAP
    // g1b N*64 u | h1b N*64 u | g2b N*32 u | w1t 8192 u | w2t 4096 u
    int*   bcur   = (int*)d_ws;                   // NB
    float* dinv   = (float*)(bcur + NB);          // N
    int*   rowbeg = (int*)(dinv + NN);            // N
    int*   rowend = rowbeg + NN;                  // N
    int*   ebuf   = rowend + NN;                  // NB*BCAP
    int*   csr    = ebuf + (size_t)NB * BCAP;     // NB*BCAP
    unsigned* g1b = (unsigned*)(csr + (size_t)NB * BCAP);  // N*64
    unsigned* h1b = g1b + (size_t)NN * 64;        // N*64
    unsigned* g2b = h1b + (size_t)NN * 64;        // N*32
    unsigned short* w1t = (unsigned short*)(g2b + (size_t)NN * 32);  // 16384 bf16
    unsigned short* w2t = w1t + 16384;                               // 8192 bf16

    constexpr int GB = 2048;          // gather blocks (persistent)
    constexpr int NW = GB * 4;        // gather waves
    constexpr int IB = (24576 + NB + 255) / 256;  // init blocks

    k_init<<<IB, 256, 0, stream>>>(W1, W2, w1t, w2t, bcur);
    k_bin<<<(EE + TILE - 1) / TILE, 256, 0, stream>>>(src, dst, bcur, ebuf, EE);
    k_csr<<<NB, 256, 0, stream>>>(bcur, ebuf, rowbeg, rowend, dinv, csr, NN);

    // layer 1: g1b = bf16((x@W1)*dinv) ; h1b = bf16(relu(dinv*(agg+g1)+b1))
    k_gemm128m<<<(NN + 63) / 64, 256, 0, stream>>>(x, w1t, dinv, g1b, NN);
    k_gather128<<<GB, 256, 0, stream>>>(rowbeg, rowend, csr, g1b, dinv, b1, h1b, NN, NW);

    // layer 2: g2b = bf16((h1b@W2)*dinv) ; out = dinv*(agg+g2)+b2  [fp32]
    k_gemm64m<<<(NN + 63) / 64, 256, 0, stream>>>((const unsigned short*)h1b, w2t, dinv, g2b, NN);
    k_gather64<<<GB, 256, 0, stream>>>(rowbeg, rowend, csr, g2b, dinv, b2, out, NN, NW);
}